// Round 3
// baseline (2132.352 us; speedup 1.0000x reference)
//
#include <hip/hip_runtime.h>
#include <cstddef>
#include <cstdint>

typedef _Float16 half8 __attribute__((ext_vector_type(8)));
typedef float floatx4 __attribute__((ext_vector_type(4)));
typedef float floatx16 __attribute__((ext_vector_type(16)));

static inline int cdiv_i(int a, int b) { return (a + b - 1) / b; }

// ---- rulebook descriptor: tbl[k*nout + o] = in (TRANSPOSED, -1 = absent)
struct RB { const int* rin; const int* rout; int K, R, nout, start, end, off; };

// ---- fused prep: feat (f16 pad8) + zero d_out + tbl init (-1) + barrier
//      counters (0) + weight pack
struct WP { const float* W; int K, Ci, CiPad, Co, start, end, off, p32; };
struct WPs {
  WP d[12];
  const float* vox; const int* vnp; _Float16* f0; int featTot, N0;
  float* dout; int outTot;
  int* tbl; int tblTot;
  int* bar; // 16 ints, zeroed each replay (harness poisons d_ws)
};
__global__ void prep_all(WPs P, _Float16* __restrict__ Bp, int total) {
  int idx = blockIdx.x * blockDim.x + threadIdx.x;
  if (idx >= total) return;
  if (idx < P.featTot) {
    int i = idx >> 3, c = idx & 7;
    float v = 0.f;
    if (i < P.N0 && c < 4) {
      const float* p = P.vox + (size_t)i * 20 + c;
      v = (p[0] + p[4] + p[8] + p[12] + p[16]) / fmaxf((float)P.vnp[i], 1.f);
    }
    P.f0[idx] = (_Float16)v;
    return;
  }
  idx -= P.featTot;
  if (idx < P.outTot) { P.dout[idx] = 0.f; return; }
  idx -= P.outTot;
  if (idx < P.tblTot) { P.tbl[idx] = -1; return; }
  idx -= P.tblTot;
  if (idx < 16) { P.bar[idx] = 0; return; }
  int widx = idx - 16;
#pragma unroll
  for (int l = 0; l < 12; ++l) {
    if (widx >= P.d[l].start && widx < P.d[l].end) {
      const WP w = P.d[l];
      int e = widx - w.start;
      int j = e & 7;
      int lane = (e >> 3) & 63;
      int rest = e >> 9;
      float v;
      if (w.p32) {
        int NT = w.Co >> 5;
        int t = rest % NT, ch = rest / NT;
        int SUB = w.CiPad >> 4;
        int ko = ch / SUB, s = ch % SUB;
        int ci = s * 16 + ((lane >> 5) << 3) + j;
        int col = t * 32 + (lane & 31);
        v = w.W[((size_t)ko * w.Ci + ci) * w.Co + col];
      } else {
        int NT = w.Co >> 4;
        int t = rest % NT, ch = rest / NT;
        int kk = ch * 32 + ((lane >> 4) << 3) + j;
        int k = kk / w.CiPad, ci = kk % w.CiPad;
        int n = t * 16 + (lane & 15);
        v = (k < w.K && ci < w.Ci) ? w.W[((size_t)k * w.Ci + ci) * w.Co + n] : 0.f;
      }
      Bp[w.off + e] = (_Float16)v;
    }
  }
}

// ---- persistent-kernel pieces --------------------------------------------

struct LCfg {
  const _Float16* fin; _Float16* fout; const _Float16* bp;
  const int* tbl; const float* sc; const float* bi; int nout, nin;
};

struct PK {
  RB rb[8]; int totFill; int* tblBase;
  LCfg L[12];
  const int* batch; int no; float* dout;
  int* bar; int nblk;
};

// one-shot grid barrier: counters pre-zeroed by prep_all each replay.
// agent-scope ACQ_REL add (release: L2 writeback) + ACQUIRE spin load
// (acquire: L1/L2 invalidate) handles cross-XCD non-coherence.
__device__ __forceinline__ void gsync(int* c, int nblk) {
  __syncthreads();  // drains vmcnt for all waves of this block
  if (threadIdx.x == 0) {
    __hip_atomic_fetch_add(c, 1, __ATOMIC_ACQ_REL, __HIP_MEMORY_SCOPE_AGENT);
    while (__hip_atomic_load(c, __ATOMIC_ACQUIRE, __HIP_MEMORY_SCOPE_AGENT) < nblk)
      __builtin_amdgcn_s_sleep(8);
  }
  __syncthreads();
}

// per-wave 16x16x32 conv layer (KS=1, no LDS), grid-strided over row tiles
template <int K, int CiPad, int Co, int CB>
__device__ void conv16_layer(const LCfg L, int gw, int GW) {
  constexpr int NT = Co / 16;
  constexpr int NTW = NT / CB;
  static_assert(NT % CB == 0 && NTW >= 1);
  constexpr int NCH = (K * CiPad + 31) / 32;
  constexpr int L2C = (CiPad == 8) ? 3 : 4;
  constexpr int DIV = (CiPad >= 32) ? (CiPad / 32) : 1;
  const int lane = threadIdx.x & 63;
  const int m = lane & 15, lb = (lane >> 4) * 8;
  if (gw == 0) {  // zero pad row of output (read via idx==nin next layer)
    for (int c = lane; c < Co; c += 64)
      L.fout[(size_t)L.nout * Co + c] = (_Float16)0.f;
  }
  const int ntile = ((L.nout + 15) >> 4) * CB;
  for (int it = gw; it < ntile; it += GW) {
    const int rt = it / CB, cb = it % CB;
    const int i0 = rt * 16;
    const int row = i0 + m;
    const bool rOK = row < L.nout;
    const int ct0 = cb * NTW;
    floatx4 acc[NTW];
#pragma unroll
    for (int n = 0; n < NTW; ++n) { floatx4 z = {0, 0, 0, 0}; acc[n] = z; }

    if constexpr (CiPad >= 32) {
      constexpr int NC = K * DIV;
      constexpr int DA = NC < 8 ? NC : 8;
      constexpr int DB = NC < 2 ? NC : 2;
      int idx[K];
#pragma unroll
      for (int q = 0; q < K; ++q) {
        int jj = rOK ? L.tbl[(size_t)q * L.nout + row] : -1;
        idx[q] = (jj < 0) ? L.nin : jj;
      }
      half8 ap[DA]; half8 bq[DB][NTW];
#pragma unroll
      for (int d = 0; d < DA; ++d)
        ap[d] = *(const half8*)(L.fin + (size_t)idx[d / DIV] * CiPad + (d % DIV) * 32 + lb);
#pragma unroll
      for (int d = 0; d < DB; ++d) {
        int ch = (d / DIV) * DIV + (d % DIV);
#pragma unroll
        for (int n = 0; n < NTW; ++n)
          bq[d][n] = *(const half8*)(L.bp + ((size_t)ch * NT * 64 + lane) * 8 +
                                     (size_t)(ct0 + n) * 512);
      }
#pragma unroll
      for (int ii = 0; ii < NC; ++ii) {
        half8 a = ap[ii % DA];
        half8 bt[NTW];
#pragma unroll
        for (int n = 0; n < NTW; ++n) bt[n] = bq[ii % DB][n];
        if (ii + DA < NC) {
          int nx = ii + DA;
          ap[ii % DA] = *(const half8*)(L.fin + (size_t)idx[nx / DIV] * CiPad +
                                        (nx % DIV) * 32 + lb);
        }
        if (ii + DB < NC) {
          int nx = ii + DB;
#pragma unroll
          for (int n = 0; n < NTW; ++n)
            bq[ii % DB][n] = *(const half8*)(L.bp + ((size_t)nx * NT * 64 + lane) * 8 +
                                             (size_t)(ct0 + n) * 512);
        }
#pragma unroll
        for (int n = 0; n < NTW; ++n)
          acc[n] = __builtin_amdgcn_mfma_f32_16x16x32_f16(a, bt[n], acc[n], 0, 0, 0);
      }
    } else {
      constexpr int NCW = NCH;
      constexpr int DA = NCW < 8 ? NCW : 8;
      constexpr int DB = NCW < 2 ? NCW : 2;
      int idx[NCW];
#pragma unroll
      for (int q = 0; q < NCW; ++q) {
        int ko = (q * 32 + lb) >> L2C;
        int jj = (rOK && ko < K) ? L.tbl[(size_t)ko * L.nout + row] : -1;
        idx[q] = (jj < 0) ? L.nin : jj;
      }
      half8 ap[DA]; half8 bq[DB][NTW];
#pragma unroll
      for (int d = 0; d < DA; ++d)
        ap[d] = *(const half8*)(L.fin + (size_t)idx[d] * CiPad + ((d * 32 + lb) & (CiPad - 1)));
#pragma unroll
      for (int d = 0; d < DB; ++d) {
#pragma unroll
        for (int n = 0; n < NTW; ++n)
          bq[d][n] = *(const half8*)(L.bp + ((size_t)d * NT * 64 + lane) * 8 +
                                     (size_t)(ct0 + n) * 512);
      }
#pragma unroll
      for (int ii = 0; ii < NCW; ++ii) {
        half8 a = ap[ii % DA];
        half8 bt[NTW];
#pragma unroll
        for (int n = 0; n < NTW; ++n) bt[n] = bq[ii % DB][n];
        if (ii + DA < NCW) {
          int nx = ii + DA;
          ap[ii % DA] = *(const half8*)(L.fin + (size_t)idx[nx] * CiPad +
                                        ((nx * 32 + lb) & (CiPad - 1)));
        }
        if (ii + DB < NCW) {
          int nx = ii + DB;
#pragma unroll
          for (int n = 0; n < NTW; ++n)
            bq[ii % DB][n] = *(const half8*)(L.bp + ((size_t)nx * NT * 64 + lane) * 8 +
                                             (size_t)(ct0 + n) * 512);
        }
#pragma unroll
        for (int n = 0; n < NTW; ++n)
          acc[n] = __builtin_amdgcn_mfma_f32_16x16x32_f16(a, bt[n], acc[n], 0, 0, 0);
      }
    }

    const int rl = (lane >> 4) * 4;
#pragma unroll
    for (int n = 0; n < NTW; ++n) {
      int col = (ct0 + n) * 16 + m;
      float s_ = L.sc[col], b_ = L.bi[col];
#pragma unroll
      for (int r = 0; r < 4; ++r) {
        int orow = i0 + rl + r;
        if (orow < L.nout)
          L.fout[(size_t)orow * Co + col] = (_Float16)fmaxf(fmaf(acc[n][r], s_, b_), 0.f);
      }
    }
  }
}

// per-wave 32x32x16 conv layer (KS=1, no LDS), grid-strided over row tiles
template <int K, int CiPad, int Co, int CB>
__device__ void conv32_layer(const LCfg L, int gw, int GW) {
  constexpr int NT = Co / 32;
  constexpr int NTW = NT / CB;
  static_assert(NT % CB == 0 && NTW >= 1);
  constexpr int SUB = CiPad / 16;
  constexpr int NC = K * SUB;
  constexpr int DA = NC < 8 ? NC : 8;
  constexpr int DB = NC < 2 ? NC : 2;
  const int lane = threadIdx.x & 63;
  const int m = lane & 31, lb = (lane >> 5) * 8, h = lane >> 5;
  if (gw == 0) {
    for (int c = lane; c < Co; c += 64)
      L.fout[(size_t)L.nout * Co + c] = (_Float16)0.f;
  }
  const int ntile = ((L.nout + 31) >> 5) * CB;
  for (int it = gw; it < ntile; it += GW) {
    const int rt = it / CB, cb = it % CB;
    const int i0 = rt * 32;
    const int row = i0 + m;
    const bool rOK = row < L.nout;
    const int ct0 = cb * NTW;
    floatx16 acc[NTW];
#pragma unroll
    for (int n = 0; n < NTW; ++n)
#pragma unroll
      for (int r = 0; r < 16; ++r) acc[n][r] = 0.f;

    int idx[K];
#pragma unroll
    for (int q = 0; q < K; ++q) {
      int jj = rOK ? L.tbl[(size_t)q * L.nout + row] : -1;
      idx[q] = (jj < 0) ? L.nin : jj;
    }
    half8 ap[DA]; half8 bq[DB][NTW];
#pragma unroll
    for (int d = 0; d < DA; ++d)
      ap[d] = *(const half8*)(L.fin + (size_t)idx[d / SUB] * CiPad + (d % SUB) * 16 + lb);
#pragma unroll
    for (int d = 0; d < DB; ++d) {
#pragma unroll
      for (int n = 0; n < NTW; ++n)
        bq[d][n] = *(const half8*)(L.bp + (size_t)(d * NT + ct0 + n) * 512 + lane * 8);
    }
#pragma unroll
    for (int ii = 0; ii < NC; ++ii) {
      half8 a = ap[ii % DA];
      half8 bt[NTW];
#pragma unroll
      for (int n = 0; n < NTW; ++n) bt[n] = bq[ii % DB][n];
      if (ii + DA < NC) {
        int nx = ii + DA;
        ap[ii % DA] = *(const half8*)(L.fin + (size_t)idx[nx / SUB] * CiPad +
                                      (nx % SUB) * 16 + lb);
      }
      if (ii + DB < NC) {
        int nx = ii + DB;
#pragma unroll
        for (int n = 0; n < NTW; ++n)
          bq[ii % DB][n] = *(const half8*)(L.bp + (size_t)(nx * NT + ct0 + n) * 512 + lane * 8);
      }
#pragma unroll
      for (int n = 0; n < NTW; ++n)
        acc[n] = __builtin_amdgcn_mfma_f32_32x32x16_f16(a, bt[n], acc[n], 0, 0, 0);
    }

#pragma unroll
    for (int n = 0; n < NTW; ++n) {
      int col = (ct0 + n) * 32 + m;
      float s_ = L.sc[col], b_ = L.bi[col];
#pragma unroll
      for (int reg = 0; reg < 16; ++reg) {
        int orow = i0 + (reg & 3) + 8 * (reg >> 2) + 4 * h;
        if (orow < L.nout)
          L.fout[(size_t)orow * Co + col] = (_Float16)fmaxf(fmaf(acc[n][reg], s_, b_), 0.f);
      }
    }
  }
}

// grid = 256 blocks x 1024 threads: 16 waves/block, VGPR<=128 (launch_bounds)
// and LDS=0 guarantee >=1 block/CU => all 256 blocks co-resident => the
// software grid barrier cannot deadlock.
__global__ __launch_bounds__(1024) void net_persistent(PK P) {
  const int nblk = P.nblk;
  // phase -1: rulebook inversion (grid-strided scatter)
  {
    const int nthr = gridDim.x * 1024;
    for (int idx = blockIdx.x * 1024 + threadIdx.x; idx < P.totFill; idx += nthr) {
#pragma unroll
      for (int l = 0; l < 8; ++l) {
        if (idx >= P.rb[l].start && idx < P.rb[l].end) {
          const RB rb = P.rb[l];
          int e = idx - rb.start;
          int o = rb.rout[e];
          if ((unsigned)o < (unsigned)rb.nout) {
            int k = e / rb.R;
            P.tblBase[rb.off + (size_t)k * rb.nout + o] = rb.rin[e];
          }
        }
      }
    }
  }
  gsync(P.bar + 0, nblk);
  const int gw = blockIdx.x * 16 + (threadIdx.x >> 6);
  const int GW = gridDim.x * 16;
  conv16_layer<27, 8, 16, 1>(P.L[0], gw, GW);   gsync(P.bar + 1, nblk);
  conv16_layer<27, 16, 16, 1>(P.L[1], gw, GW);  gsync(P.bar + 2, nblk);
  conv16_layer<27, 16, 32, 1>(P.L[2], gw, GW);  gsync(P.bar + 3, nblk);
  conv32_layer<27, 32, 32, 1>(P.L[3], gw, GW);  gsync(P.bar + 4, nblk);
  conv32_layer<27, 32, 32, 1>(P.L[4], gw, GW);  gsync(P.bar + 5, nblk);
  conv32_layer<27, 32, 64, 2>(P.L[5], gw, GW);  gsync(P.bar + 6, nblk);
  conv32_layer<27, 64, 64, 2>(P.L[6], gw, GW);  gsync(P.bar + 7, nblk);
  conv32_layer<27, 64, 64, 2>(P.L[7], gw, GW);  gsync(P.bar + 8, nblk);
  conv32_layer<27, 64, 64, 2>(P.L[8], gw, GW);  gsync(P.bar + 9, nblk);
  conv32_layer<27, 64, 64, 2>(P.L[9], gw, GW);  gsync(P.bar + 10, nblk);
  conv32_layer<27, 64, 64, 2>(P.L[10], gw, GW); gsync(P.bar + 11, nblk);
  conv16_layer<3, 64, 128, 4>(P.L[11], gw, GW); gsync(P.bar + 12, nblk);
  // segmax: batch nondecreasing; run-length local max then one atomic per run
  {
    const _Float16* x = (const _Float16*)P.L[11].fout;
    int c = threadIdx.x & 127;
    int g = blockIdx.x * 8 + (threadIdx.x >> 7);
    int G = gridDim.x * 8;
    int per = (P.no + G - 1) / G;
    int r0 = g * per;
    int rend = min(P.no, r0 + per);
    float mx = 0.f;
    int cb = -1;
    for (int r = r0; r < rend; ++r) {
      int b = P.batch[r];
      if (b != cb) {
        if (cb >= 0) atomicMax((int*)P.dout + ((size_t)cb << 7) + c, __float_as_int(mx));
        cb = b; mx = 0.f;
      }
      mx = fmaxf(mx, (float)x[(size_t)r * 128 + c]);
    }
    if (cb >= 0) atomicMax((int*)P.dout + ((size_t)cb << 7) + c, __float_as_int(mx));
  }
}

extern "C" void kernel_launch(void* const* d_in, const int* in_sizes, int n_in,
                              void* d_out, int out_size, void* d_ws, size_t ws_size,
                              hipStream_t stream) {
  auto I = [&](int idx) { return (const int*)d_in[idx]; };
  auto F = [&](int idx) { return (const float*)d_in[idx]; };

  const int N0  = in_sizes[1];
  const int R1  = in_sizes[3] / 27;
  const int R2s = in_sizes[5] / 27;
  const int n2  = in_sizes[7];
  const int R2  = in_sizes[8] / 27;
  const int R3s = in_sizes[10] / 27;
  const int n3  = in_sizes[12];
  const int R3  = in_sizes[13] / 27;
  const int R4s = in_sizes[15] / 27;
  const int n4  = in_sizes[17];
  const int R4  = in_sizes[18] / 27;
  const int Ro  = in_sizes[20] / 3;
  const int no  = in_sizes[22];

  const int wIdx[12] = {23, 26, 29, 32, 35, 38, 41, 44, 47, 50, 53, 56};
  const int Ks[12]   = {27, 27, 27, 27, 27, 27, 27, 27, 27, 27, 27, 3};
  const int Cis[12]  = {4, 16, 16, 32, 32, 32, 64, 64, 64, 64, 64, 64};
  const int Cos[12]  = {16, 16, 32, 32, 32, 64, 64, 64, 64, 64, 64, 128};
  const int P32[12]  = {0, 0, 0, 1, 1, 1, 1, 1, 1, 1, 1, 0};
  WPs P;
  int wtot = 0;
  int bpOff[12];
  for (int l = 0; l < 12; ++l) {
    int cip = Cis[l] < 8 ? 8 : Cis[l];
    int sz;
    if (P32[l]) sz = Ks[l] * (cip / 16) * (Cos[l] / 32) * 512;
    else        sz = ((Ks[l] * cip + 31) / 32) * (Cos[l] / 16) * 512;
    P.d[l].W = F(wIdx[l]);
    P.d[l].K = Ks[l]; P.d[l].Ci = Cis[l]; P.d[l].CiPad = cip; P.d[l].Co = Cos[l];
    P.d[l].start = wtot; P.d[l].end = wtot + sz; P.d[l].off = wtot; P.d[l].p32 = P32[l];
    bpOff[l] = wtot;
    wtot += sz;
  }

  PK K;
  const int rbRin[8]  = {3, 5, 8, 10, 13, 15, 18, 20};
  const int rbRs[8]   = {R1, R2s, R2, R3s, R3, R4s, R4, Ro};
  const int rbKs[8]   = {27, 27, 27, 27, 27, 27, 27, 3};
  const int rbNout[8] = {N0, n2, n2, n3, n3, n4, n4, no};
  size_t tblOff[8];
  size_t totTbl = 0;
  int totFill = 0;
  for (int l = 0; l < 8; ++l) {
    tblOff[l] = totTbl;
    totTbl += (size_t)rbNout[l] * rbKs[l];
    K.rb[l].rin = I(rbRin[l]);
    K.rb[l].rout = I(rbRin[l] + 1);
    K.rb[l].K = rbKs[l]; K.rb[l].R = rbRs[l]; K.rb[l].nout = rbNout[l];
    K.rb[l].start = totFill;
    totFill += rbKs[l] * rbRs[l];
    K.rb[l].end = totFill;
    K.rb[l].off = (int)tblOff[l];
  }
  K.totFill = totFill;

  size_t S = (size_t)(N0 + 1) * 16;
  auto smax = [&](size_t v) { if (v > S) S = v; };
  smax((size_t)(n2 + 1) * 32);
  smax((size_t)(n3 + 1) * 64);
  smax((size_t)(n4 + 1) * 64);
  smax((size_t)(no + 1) * 128);
  S = (S + 7) & ~(size_t)7;

  _Float16* h = (_Float16*)d_ws;
  size_t off = 0;
  _Float16* f0 = h + off;   off += (size_t)(N0 + 1) * 8;
  _Float16* bufA = h + off; off += S;
  _Float16* bufB = h + off; off += S;
  _Float16* Bp = h + off;   off += (size_t)((wtot + 7) & ~7);
  int* tblBase = (int*)(h + off);
  int* bar = tblBase + totTbl;
  K.tblBase = tblBase;
  K.bar = bar;
  K.nblk = 256;

  // fused prep: feat + zero d_out + tbl init (-1) + barrier zero + weights
  P.vox = F(0); P.vnp = I(1); P.f0 = f0;
  P.featTot = (N0 + 1) * 8; P.N0 = N0;
  P.dout = (float*)d_out; P.outTot = out_size;
  P.tbl = tblBase; P.tblTot = (int)totTbl;
  P.bar = bar;
  int prepTot = P.featTot + P.outTot + P.tblTot + 16 + wtot;
  prep_all<<<cdiv_i(prepTot, 256), 256, 0, stream>>>(P, Bp, prepTot);

  // layer wiring (ping-pong f0 -> A -> B -> ...)
  const int l2rb[12] = {0, 0, 1, 2, 2, 3, 4, 4, 5, 6, 6, 7};
  const int louts[12] = {N0, N0, n2, n2, n2, n3, n3, n3, n4, n4, n4, no};
  const int lins[12]  = {N0, N0, N0, n2, n2, n2, n3, n3, n3, n4, n4, n4};
  _Float16* bufs[13];
  bufs[0] = f0;
  for (int l = 0; l < 12; ++l) bufs[l + 1] = (l & 1) ? bufB : bufA;
  // f0 -> bufA -> bufB -> bufA -> ... (bufs[1]=A, bufs[2]=B, ...)
  for (int l = 0; l < 12; ++l) {
    K.L[l].fin  = bufs[l];
    K.L[l].fout = bufs[l + 1];
    K.L[l].bp   = Bp + bpOff[l];
    K.L[l].tbl  = tblBase + tblOff[l2rb[l]];
    K.L[l].sc   = F(wIdx[l] + 1);
    K.L[l].bi   = F(wIdx[l] + 2);
    K.L[l].nout = louts[l];
    K.L[l].nin  = lins[l];
  }
  K.batch = I(22); K.no = no; K.dout = (float*)d_out;

  net_persistent<<<256, 1024, 0, stream>>>(K);
}

// Round 4
// 1037.025 us; speedup vs baseline: 2.0562x; 2.0562x over previous
//
#include <hip/hip_runtime.h>
#include <cstddef>
#include <cstdint>

typedef _Float16 half8 __attribute__((ext_vector_type(8)));
typedef float floatx4 __attribute__((ext_vector_type(4)));
typedef float floatx16 __attribute__((ext_vector_type(16)));

static inline int cdiv_i(int a, int b) { return (a + b - 1) / b; }

// ---- rulebook descriptor: tbl[k*nout + o] = in (TRANSPOSED, -1 = absent)
struct RB { const int* rin; const int* rout; int K, R, nout, start, end, off; };

// ---- fused prep: feat (f16 pad8) + zero d_out + tbl init (-1) + barrier
//      counters (0) + weight pack
struct WP { const float* W; int K, Ci, CiPad, Co, start, end, off, p32; };
struct WPs {
  WP d[12];
  const float* vox; const int* vnp; _Float16* f0; int featTot, N0;
  float* dout; int outTot;
  int* tbl; int tblTot;
  int* bar; // 16 ints, zeroed each replay (harness poisons d_ws)
};
__global__ void prep_all(WPs P, _Float16* __restrict__ Bp, int total) {
  int idx = blockIdx.x * blockDim.x + threadIdx.x;
  if (idx >= total) return;
  if (idx < P.featTot) {
    int i = idx >> 3, c = idx & 7;
    float v = 0.f;
    if (i < P.N0 && c < 4) {
      const float* p = P.vox + (size_t)i * 20 + c;
      v = (p[0] + p[4] + p[8] + p[12] + p[16]) / fmaxf((float)P.vnp[i], 1.f);
    }
    P.f0[idx] = (_Float16)v;
    return;
  }
  idx -= P.featTot;
  if (idx < P.outTot) { P.dout[idx] = 0.f; return; }
  idx -= P.outTot;
  if (idx < P.tblTot) { P.tbl[idx] = -1; return; }
  idx -= P.tblTot;
  if (idx < 16) { P.bar[idx] = 0; return; }
  int widx = idx - 16;
#pragma unroll
  for (int l = 0; l < 12; ++l) {
    if (widx >= P.d[l].start && widx < P.d[l].end) {
      const WP w = P.d[l];
      int e = widx - w.start;
      int j = e & 7;
      int lane = (e >> 3) & 63;
      int rest = e >> 9;
      float v;
      if (w.p32) {
        int NT = w.Co >> 5;
        int t = rest % NT, ch = rest / NT;
        int SUB = w.CiPad >> 4;
        int ko = ch / SUB, s = ch % SUB;
        int ci = s * 16 + ((lane >> 5) << 3) + j;
        int col = t * 32 + (lane & 31);
        v = w.W[((size_t)ko * w.Ci + ci) * w.Co + col];
      } else {
        int NT = w.Co >> 4;
        int t = rest % NT, ch = rest / NT;
        int kk = ch * 32 + ((lane >> 4) << 3) + j;
        int k = kk / w.CiPad, ci = kk % w.CiPad;
        int n = t * 16 + (lane & 15);
        v = (k < w.K && ci < w.Ci) ? w.W[((size_t)k * w.Ci + ci) * w.Co + n] : 0.f;
      }
      Bp[w.off + e] = (_Float16)v;
    }
  }
}

// ---- persistent-kernel pieces --------------------------------------------

struct LCfg {
  const _Float16* fin; _Float16* fout; const _Float16* bp;
  const int* tbl; const float* sc; const float* bi; int nout, nin;
};

struct PK {
  RB rb[8]; int totFill; int* tblBase;
  LCfg L[12];
  const int* batch; int no; float* dout;
  int* bar; int nblk;
};

// one-shot grid barrier, counters pre-zeroed by prep_all each replay.
// CRITICAL (round-3 lesson): fence ONCE per crossing, spin RELAXED.
// Per-poll ACQUIRE emitted an L2 invalidate every iteration -> all working
// blocks' caches perpetually cold -> 304 MB refetch / 586 MB writeback.
__device__ __forceinline__ void gsync(int* c, int nblk) {
  __syncthreads();
  if (threadIdx.x == 0) {
    __builtin_amdgcn_fence(__ATOMIC_RELEASE, "agent");  // one wbl2: publish our writes
    __hip_atomic_fetch_add(c, 1, __ATOMIC_RELAXED, __HIP_MEMORY_SCOPE_AGENT);
    while (__hip_atomic_load(c, __ATOMIC_RELAXED, __HIP_MEMORY_SCOPE_AGENT) < nblk)
      __builtin_amdgcn_s_sleep(8);                      // relaxed poll: no cache ops
    __builtin_amdgcn_fence(__ATOMIC_ACQUIRE, "agent");  // one inv: see others' writes
  }
  __syncthreads();
}

// per-wave 16x16x32 conv layer (KS=1, no LDS), grid-strided over row tiles
template <int K, int CiPad, int Co, int CB>
__device__ void conv16_layer(const LCfg L, int gw, int GW) {
  constexpr int NT = Co / 16;
  constexpr int NTW = NT / CB;
  static_assert(NT % CB == 0 && NTW >= 1);
  constexpr int NCH = (K * CiPad + 31) / 32;
  constexpr int L2C = (CiPad == 8) ? 3 : 4;
  constexpr int DIV = (CiPad >= 32) ? (CiPad / 32) : 1;
  const int lane = threadIdx.x & 63;
  const int m = lane & 15, lb = (lane >> 4) * 8;
  if (gw == 0) {  // zero pad row of output (read via idx==nin next layer)
    for (int c = lane; c < Co; c += 64)
      L.fout[(size_t)L.nout * Co + c] = (_Float16)0.f;
  }
  const int ntile = ((L.nout + 15) >> 4) * CB;
  for (int it = gw; it < ntile; it += GW) {
    const int rt = it / CB, cb = it % CB;
    const int i0 = rt * 16;
    const int row = i0 + m;
    const bool rOK = row < L.nout;
    const int ct0 = cb * NTW;
    floatx4 acc[NTW];
#pragma unroll
    for (int n = 0; n < NTW; ++n) { floatx4 z = {0, 0, 0, 0}; acc[n] = z; }

    if constexpr (CiPad >= 32) {
      constexpr int NC = K * DIV;
      constexpr int DA = NC < 8 ? NC : 8;
      constexpr int DB = NC < 2 ? NC : 2;
      int idx[K];
#pragma unroll
      for (int q = 0; q < K; ++q) {
        int jj = rOK ? L.tbl[(size_t)q * L.nout + row] : -1;
        idx[q] = (jj < 0) ? L.nin : jj;
      }
      half8 ap[DA]; half8 bq[DB][NTW];
#pragma unroll
      for (int d = 0; d < DA; ++d)
        ap[d] = *(const half8*)(L.fin + (size_t)idx[d / DIV] * CiPad + (d % DIV) * 32 + lb);
#pragma unroll
      for (int d = 0; d < DB; ++d) {
        int ch = (d / DIV) * DIV + (d % DIV);
#pragma unroll
        for (int n = 0; n < NTW; ++n)
          bq[d][n] = *(const half8*)(L.bp + ((size_t)ch * NT * 64 + lane) * 8 +
                                     (size_t)(ct0 + n) * 512);
      }
#pragma unroll
      for (int ii = 0; ii < NC; ++ii) {
        half8 a = ap[ii % DA];
        half8 bt[NTW];
#pragma unroll
        for (int n = 0; n < NTW; ++n) bt[n] = bq[ii % DB][n];
        if (ii + DA < NC) {
          int nx = ii + DA;
          ap[ii % DA] = *(const half8*)(L.fin + (size_t)idx[nx / DIV] * CiPad +
                                        (nx % DIV) * 32 + lb);
        }
        if (ii + DB < NC) {
          int nx = ii + DB;
#pragma unroll
          for (int n = 0; n < NTW; ++n)
            bq[ii % DB][n] = *(const half8*)(L.bp + ((size_t)nx * NT * 64 + lane) * 8 +
                                             (size_t)(ct0 + n) * 512);
        }
#pragma unroll
        for (int n = 0; n < NTW; ++n)
          acc[n] = __builtin_amdgcn_mfma_f32_16x16x32_f16(a, bt[n], acc[n], 0, 0, 0);
      }
    } else {
      constexpr int NCW = NCH;
      constexpr int DA = NCW < 8 ? NCW : 8;
      constexpr int DB = NCW < 2 ? NCW : 2;
      int idx[NCW];
#pragma unroll
      for (int q = 0; q < NCW; ++q) {
        int ko = (q * 32 + lb) >> L2C;
        int jj = (rOK && ko < K) ? L.tbl[(size_t)ko * L.nout + row] : -1;
        idx[q] = (jj < 0) ? L.nin : jj;
      }
      half8 ap[DA]; half8 bq[DB][NTW];
#pragma unroll
      for (int d = 0; d < DA; ++d)
        ap[d] = *(const half8*)(L.fin + (size_t)idx[d] * CiPad + ((d * 32 + lb) & (CiPad - 1)));
#pragma unroll
      for (int d = 0; d < DB; ++d) {
#pragma unroll
        for (int n = 0; n < NTW; ++n)
          bq[d][n] = *(const half8*)(L.bp + ((size_t)d * NT * 64 + lane) * 8 +
                                     (size_t)(ct0 + n) * 512);
      }
#pragma unroll
      for (int ii = 0; ii < NCW; ++ii) {
        half8 a = ap[ii % DA];
        half8 bt[NTW];
#pragma unroll
        for (int n = 0; n < NTW; ++n) bt[n] = bq[ii % DB][n];
        if (ii + DA < NCW) {
          int nx = ii + DA;
          ap[ii % DA] = *(const half8*)(L.fin + (size_t)idx[nx] * CiPad +
                                        ((nx * 32 + lb) & (CiPad - 1)));
        }
        if (ii + DB < NCW) {
          int nx = ii + DB;
#pragma unroll
          for (int n = 0; n < NTW; ++n)
            bq[ii % DB][n] = *(const half8*)(L.bp + ((size_t)nx * NT * 64 + lane) * 8 +
                                             (size_t)(ct0 + n) * 512);
        }
#pragma unroll
        for (int n = 0; n < NTW; ++n)
          acc[n] = __builtin_amdgcn_mfma_f32_16x16x32_f16(a, bt[n], acc[n], 0, 0, 0);
      }
    }

    const int rl = (lane >> 4) * 4;
#pragma unroll
    for (int n = 0; n < NTW; ++n) {
      int col = (ct0 + n) * 16 + m;
      float s_ = L.sc[col], b_ = L.bi[col];
#pragma unroll
      for (int r = 0; r < 4; ++r) {
        int orow = i0 + rl + r;
        if (orow < L.nout)
          L.fout[(size_t)orow * Co + col] = (_Float16)fmaxf(fmaf(acc[n][r], s_, b_), 0.f);
      }
    }
  }
}

// per-wave 32x32x16 conv layer (KS=1, no LDS), grid-strided over row tiles
template <int K, int CiPad, int Co, int CB>
__device__ void conv32_layer(const LCfg L, int gw, int GW) {
  constexpr int NT = Co / 32;
  constexpr int NTW = NT / CB;
  static_assert(NT % CB == 0 && NTW >= 1);
  constexpr int SUB = CiPad / 16;
  constexpr int NC = K * SUB;
  constexpr int DA = NC < 8 ? NC : 8;
  constexpr int DB = NC < 2 ? NC : 2;
  const int lane = threadIdx.x & 63;
  const int m = lane & 31, lb = (lane >> 5) * 8, h = lane >> 5;
  if (gw == 0) {
    for (int c = lane; c < Co; c += 64)
      L.fout[(size_t)L.nout * Co + c] = (_Float16)0.f;
  }
  const int ntile = ((L.nout + 31) >> 5) * CB;
  for (int it = gw; it < ntile; it += GW) {
    const int rt = it / CB, cb = it % CB;
    const int i0 = rt * 32;
    const int row = i0 + m;
    const bool rOK = row < L.nout;
    const int ct0 = cb * NTW;
    floatx16 acc[NTW];
#pragma unroll
    for (int n = 0; n < NTW; ++n)
#pragma unroll
      for (int r = 0; r < 16; ++r) acc[n][r] = 0.f;

    int idx[K];
#pragma unroll
    for (int q = 0; q < K; ++q) {
      int jj = rOK ? L.tbl[(size_t)q * L.nout + row] : -1;
      idx[q] = (jj < 0) ? L.nin : jj;
    }
    half8 ap[DA]; half8 bq[DB][NTW];
#pragma unroll
    for (int d = 0; d < DA; ++d)
      ap[d] = *(const half8*)(L.fin + (size_t)idx[d / SUB] * CiPad + (d % SUB) * 16 + lb);
#pragma unroll
    for (int d = 0; d < DB; ++d) {
#pragma unroll
      for (int n = 0; n < NTW; ++n)
        bq[d][n] = *(const half8*)(L.bp + (size_t)(d * NT + ct0 + n) * 512 + lane * 8);
    }
#pragma unroll
    for (int ii = 0; ii < NC; ++ii) {
      half8 a = ap[ii % DA];
      half8 bt[NTW];
#pragma unroll
      for (int n = 0; n < NTW; ++n) bt[n] = bq[ii % DB][n];
      if (ii + DA < NC) {
        int nx = ii + DA;
        ap[ii % DA] = *(const half8*)(L.fin + (size_t)idx[nx / SUB] * CiPad +
                                      (nx % SUB) * 16 + lb);
      }
      if (ii + DB < NC) {
        int nx = ii + DB;
#pragma unroll
        for (int n = 0; n < NTW; ++n)
          bq[ii % DB][n] = *(const half8*)(L.bp + (size_t)(nx * NT + ct0 + n) * 512 + lane * 8);
      }
#pragma unroll
      for (int n = 0; n < NTW; ++n)
        acc[n] = __builtin_amdgcn_mfma_f32_32x32x16_f16(a, bt[n], acc[n], 0, 0, 0);
    }

#pragma unroll
    for (int n = 0; n < NTW; ++n) {
      int col = (ct0 + n) * 32 + m;
      float s_ = L.sc[col], b_ = L.bi[col];
#pragma unroll
      for (int reg = 0; reg < 16; ++reg) {
        int orow = i0 + (reg & 3) + 8 * (reg >> 2) + 4 * h;
        if (orow < L.nout)
          L.fout[(size_t)orow * Co + col] = (_Float16)fmaxf(fmaf(acc[n][reg], s_, b_), 0.f);
      }
    }
  }
}

// grid = 256 blocks x 1024 threads: 16 waves/block, VGPR<=128 (launch_bounds)
// and LDS=0 guarantee >=1 block/CU => all 256 blocks co-resident => the
// software grid barrier cannot deadlock.
__global__ __launch_bounds__(1024) void net_persistent(PK P) {
  const int nblk = P.nblk;
  // phase -1: rulebook inversion (grid-strided scatter)
  {
    const int nthr = gridDim.x * 1024;
    for (int idx = blockIdx.x * 1024 + threadIdx.x; idx < P.totFill; idx += nthr) {
#pragma unroll
      for (int l = 0; l < 8; ++l) {
        if (idx >= P.rb[l].start && idx < P.rb[l].end) {
          const RB rb = P.rb[l];
          int e = idx - rb.start;
          int o = rb.rout[e];
          if ((unsigned)o < (unsigned)rb.nout) {
            int k = e / rb.R;
            P.tblBase[rb.off + (size_t)k * rb.nout + o] = rb.rin[e];
          }
        }
      }
    }
  }
  gsync(P.bar + 0, nblk);
  const int gw = blockIdx.x * 16 + (threadIdx.x >> 6);
  const int GW = gridDim.x * 16;
  conv16_layer<27, 8, 16, 1>(P.L[0], gw, GW);   gsync(P.bar + 1, nblk);
  conv16_layer<27, 16, 16, 1>(P.L[1], gw, GW);  gsync(P.bar + 2, nblk);
  conv16_layer<27, 16, 32, 1>(P.L[2], gw, GW);  gsync(P.bar + 3, nblk);
  conv32_layer<27, 32, 32, 1>(P.L[3], gw, GW);  gsync(P.bar + 4, nblk);
  conv32_layer<27, 32, 32, 1>(P.L[4], gw, GW);  gsync(P.bar + 5, nblk);
  conv32_layer<27, 32, 64, 2>(P.L[5], gw, GW);  gsync(P.bar + 6, nblk);
  conv32_layer<27, 64, 64, 2>(P.L[6], gw, GW);  gsync(P.bar + 7, nblk);
  conv32_layer<27, 64, 64, 2>(P.L[7], gw, GW);  gsync(P.bar + 8, nblk);
  conv32_layer<27, 64, 64, 2>(P.L[8], gw, GW);  gsync(P.bar + 9, nblk);
  conv32_layer<27, 64, 64, 2>(P.L[9], gw, GW);  gsync(P.bar + 10, nblk);
  conv32_layer<27, 64, 64, 2>(P.L[10], gw, GW); gsync(P.bar + 11, nblk);
  conv16_layer<3, 64, 128, 4>(P.L[11], gw, GW); gsync(P.bar + 12, nblk);
  // segmax: batch nondecreasing; run-length local max then one atomic per run
  {
    const _Float16* x = (const _Float16*)P.L[11].fout;
    int c = threadIdx.x & 127;
    int g = blockIdx.x * 8 + (threadIdx.x >> 7);
    int G = gridDim.x * 8;
    int per = (P.no + G - 1) / G;
    int r0 = g * per;
    int rend = min(P.no, r0 + per);
    float mx = 0.f;
    int cb = -1;
    for (int r = r0; r < rend; ++r) {
      int b = P.batch[r];
      if (b != cb) {
        if (cb >= 0) atomicMax((int*)P.dout + ((size_t)cb << 7) + c, __float_as_int(mx));
        cb = b; mx = 0.f;
      }
      mx = fmaxf(mx, (float)x[(size_t)r * 128 + c]);
    }
    if (cb >= 0) atomicMax((int*)P.dout + ((size_t)cb << 7) + c, __float_as_int(mx));
  }
}

extern "C" void kernel_launch(void* const* d_in, const int* in_sizes, int n_in,
                              void* d_out, int out_size, void* d_ws, size_t ws_size,
                              hipStream_t stream) {
  auto I = [&](int idx) { return (const int*)d_in[idx]; };
  auto F = [&](int idx) { return (const float*)d_in[idx]; };

  const int N0  = in_sizes[1];
  const int R1  = in_sizes[3] / 27;
  const int R2s = in_sizes[5] / 27;
  const int n2  = in_sizes[7];
  const int R2  = in_sizes[8] / 27;
  const int R3s = in_sizes[10] / 27;
  const int n3  = in_sizes[12];
  const int R3  = in_sizes[13] / 27;
  const int R4s = in_sizes[15] / 27;
  const int n4  = in_sizes[17];
  const int R4  = in_sizes[18] / 27;
  const int Ro  = in_sizes[20] / 3;
  const int no  = in_sizes[22];

  const int wIdx[12] = {23, 26, 29, 32, 35, 38, 41, 44, 47, 50, 53, 56};
  const int Ks[12]   = {27, 27, 27, 27, 27, 27, 27, 27, 27, 27, 27, 3};
  const int Cis[12]  = {4, 16, 16, 32, 32, 32, 64, 64, 64, 64, 64, 64};
  const int Cos[12]  = {16, 16, 32, 32, 32, 64, 64, 64, 64, 64, 64, 128};
  const int P32[12]  = {0, 0, 0, 1, 1, 1, 1, 1, 1, 1, 1, 0};
  WPs P;
  int wtot = 0;
  int bpOff[12];
  for (int l = 0; l < 12; ++l) {
    int cip = Cis[l] < 8 ? 8 : Cis[l];
    int sz;
    if (P32[l]) sz = Ks[l] * (cip / 16) * (Cos[l] / 32) * 512;
    else        sz = ((Ks[l] * cip + 31) / 32) * (Cos[l] / 16) * 512;
    P.d[l].W = F(wIdx[l]);
    P.d[l].K = Ks[l]; P.d[l].Ci = Cis[l]; P.d[l].CiPad = cip; P.d[l].Co = Cos[l];
    P.d[l].start = wtot; P.d[l].end = wtot + sz; P.d[l].off = wtot; P.d[l].p32 = P32[l];
    bpOff[l] = wtot;
    wtot += sz;
  }

  PK K;
  const int rbRin[8]  = {3, 5, 8, 10, 13, 15, 18, 20};
  const int rbRs[8]   = {R1, R2s, R2, R3s, R3, R4s, R4, Ro};
  const int rbKs[8]   = {27, 27, 27, 27, 27, 27, 27, 3};
  const int rbNout[8] = {N0, n2, n2, n3, n3, n4, n4, no};
  size_t tblOff[8];
  size_t totTbl = 0;
  int totFill = 0;
  for (int l = 0; l < 8; ++l) {
    tblOff[l] = totTbl;
    totTbl += (size_t)rbNout[l] * rbKs[l];
    K.rb[l].rin = I(rbRin[l]);
    K.rb[l].rout = I(rbRin[l] + 1);
    K.rb[l].K = rbKs[l]; K.rb[l].R = rbRs[l]; K.rb[l].nout = rbNout[l];
    K.rb[l].start = totFill;
    totFill += rbKs[l] * rbRs[l];
    K.rb[l].end = totFill;
    K.rb[l].off = (int)tblOff[l];
  }
  K.totFill = totFill;

  size_t S = (size_t)(N0 + 1) * 16;
  auto smax = [&](size_t v) { if (v > S) S = v; };
  smax((size_t)(n2 + 1) * 32);
  smax((size_t)(n3 + 1) * 64);
  smax((size_t)(n4 + 1) * 64);
  smax((size_t)(no + 1) * 128);
  S = (S + 7) & ~(size_t)7;

  _Float16* h = (_Float16*)d_ws;
  size_t off = 0;
  _Float16* f0 = h + off;   off += (size_t)(N0 + 1) * 8;
  _Float16* bufA = h + off; off += S;
  _Float16* bufB = h + off; off += S;
  _Float16* Bp = h + off;   off += (size_t)((wtot + 7) & ~7);
  int* tblBase = (int*)(h + off);
  int* bar = tblBase + totTbl;
  K.tblBase = tblBase;
  K.bar = bar;
  K.nblk = 256;

  // fused prep: feat + zero d_out + tbl init (-1) + barrier zero + weights
  P.vox = F(0); P.vnp = I(1); P.f0 = f0;
  P.featTot = (N0 + 1) * 8; P.N0 = N0;
  P.dout = (float*)d_out; P.outTot = out_size;
  P.tbl = tblBase; P.tblTot = (int)totTbl;
  P.bar = bar;
  int prepTot = P.featTot + P.outTot + P.tblTot + 16 + wtot;
  prep_all<<<cdiv_i(prepTot, 256), 256, 0, stream>>>(P, Bp, prepTot);

  // layer wiring (ping-pong f0 -> A -> B -> ...)
  const int l2rb[12] = {0, 0, 1, 2, 2, 3, 4, 4, 5, 6, 6, 7};
  const int louts[12] = {N0, N0, n2, n2, n2, n3, n3, n3, n4, n4, n4, no};
  const int lins[12]  = {N0, N0, N0, n2, n2, n2, n3, n3, n3, n4, n4, n4};
  _Float16* bufs[13];
  bufs[0] = f0;
  for (int l = 0; l < 12; ++l) bufs[l + 1] = (l & 1) ? bufB : bufA;
  // f0 -> bufA -> bufB -> bufA -> ... (bufs[1]=A, bufs[2]=B, ...)
  for (int l = 0; l < 12; ++l) {
    K.L[l].fin  = bufs[l];
    K.L[l].fout = bufs[l + 1];
    K.L[l].bp   = Bp + bpOff[l];
    K.L[l].tbl  = tblBase + tblOff[l2rb[l]];
    K.L[l].sc   = F(wIdx[l] + 1);
    K.L[l].bi   = F(wIdx[l] + 2);
    K.L[l].nout = louts[l];
    K.L[l].nin  = lins[l];
  }
  K.batch = I(22); K.no = no; K.dout = (float*)d_out;

  net_persistent<<<256, 1024, 0, stream>>>(K);
}

// Round 5
// 818.129 us; speedup vs baseline: 2.6064x; 1.2676x over previous
//
#include <hip/hip_runtime.h>
#include <cstddef>
#include <cstdint>

typedef _Float16 half8 __attribute__((ext_vector_type(8)));
typedef float floatx4 __attribute__((ext_vector_type(4)));
typedef float floatx16 __attribute__((ext_vector_type(16)));

static inline int cdiv_i(int a, int b) { return (a + b - 1) / b; }

// ---- rulebook descriptor: tbl[k*nout + o] = in (TRANSPOSED, -1 = absent)
struct RB { const int* rin; const int* rout; int K, R, nout, start, end, off; };

// ---- fused prep: feat (f16 pad8) + zero d_out + tbl init (-1) + barrier
//      counters (0) + weight pack
struct WP { const float* W; int K, Ci, CiPad, Co, start, end, off, p32; };
struct WPs {
  WP d[12];
  const float* vox; const int* vnp; _Float16* f0; int featTot, N0;
  float* dout; int outTot;
  int* tbl; int tblTot;
  int* bar; // 16 ints, zeroed each replay (harness poisons d_ws)
};
__global__ void prep_all(WPs P, _Float16* __restrict__ Bp, int total) {
  int idx = blockIdx.x * blockDim.x + threadIdx.x;
  if (idx >= total) return;
  if (idx < P.featTot) {
    int i = idx >> 3, c = idx & 7;
    float v = 0.f;
    if (i < P.N0 && c < 4) {
      const float* p = P.vox + (size_t)i * 20 + c;
      v = (p[0] + p[4] + p[8] + p[12] + p[16]) / fmaxf((float)P.vnp[i], 1.f);
    }
    P.f0[idx] = (_Float16)v;
    return;
  }
  idx -= P.featTot;
  if (idx < P.outTot) { P.dout[idx] = 0.f; return; }
  idx -= P.outTot;
  if (idx < P.tblTot) { P.tbl[idx] = -1; return; }
  idx -= P.tblTot;
  if (idx < 16) { P.bar[idx] = 0; return; }
  int widx = idx - 16;
#pragma unroll
  for (int l = 0; l < 12; ++l) {
    if (widx >= P.d[l].start && widx < P.d[l].end) {
      const WP w = P.d[l];
      int e = widx - w.start;
      int j = e & 7;
      int lane = (e >> 3) & 63;
      int rest = e >> 9;
      float v;
      if (w.p32) {
        int NT = w.Co >> 5;
        int t = rest % NT, ch = rest / NT;
        int SUB = w.CiPad >> 4;
        int ko = ch / SUB, s = ch % SUB;
        int ci = s * 16 + ((lane >> 5) << 3) + j;
        int col = t * 32 + (lane & 31);
        v = w.W[((size_t)ko * w.Ci + ci) * w.Co + col];
      } else {
        int NT = w.Co >> 4;
        int t = rest % NT, ch = rest / NT;
        int kk = ch * 32 + ((lane >> 4) << 3) + j;
        int k = kk / w.CiPad, ci = kk % w.CiPad;
        int n = t * 16 + (lane & 15);
        v = (k < w.K && ci < w.Ci) ? w.W[((size_t)k * w.Ci + ci) * w.Co + n] : 0.f;
      }
      Bp[w.off + e] = (_Float16)v;
    }
  }
}

// ---- persistent-kernel pieces --------------------------------------------

struct LCfg {
  const _Float16* fin; _Float16* fout; const _Float16* bp;
  const int* tbl; const float* sc; const float* bi; int nout, nin;
};

struct PK {
  RB rb[8]; int totFill; int* tblBase;
  LCfg L[12];
  const int* batch; int no; float* dout;
  int* bar; int nblk;
};

// one-shot grid barrier, counters pre-zeroed by prep_all each replay.
// Round-3 lesson: fence ONCE per crossing, spin RELAXED (per-poll ACQUIRE
// serialized at ~2.5x cost). Round-4 lesson: the 305/587MB traffic was VGPR
// spill scratch (launch_bounds(1024) -> 64 VGPR), not barrier cache ops.
__device__ __forceinline__ void gsync(int* c, int nblk) {
  __syncthreads();
  if (threadIdx.x == 0) {
    __builtin_amdgcn_fence(__ATOMIC_RELEASE, "agent");  // one wbl2: publish our writes
    __hip_atomic_fetch_add(c, 1, __ATOMIC_RELAXED, __HIP_MEMORY_SCOPE_AGENT);
    while (__hip_atomic_load(c, __ATOMIC_RELAXED, __HIP_MEMORY_SCOPE_AGENT) < nblk)
      __builtin_amdgcn_s_sleep(8);                      // relaxed poll: no cache ops
    __builtin_amdgcn_fence(__ATOMIC_ACQUIRE, "agent");  // one inv: see others' writes
  }
  __syncthreads();
}

// per-wave 16x16x32 conv layer (KS=1, no LDS), grid-strided over row tiles
template <int K, int CiPad, int Co, int CB>
__device__ void conv16_layer(const LCfg L, int gw, int GW) {
  constexpr int NT = Co / 16;
  constexpr int NTW = NT / CB;
  static_assert(NT % CB == 0 && NTW >= 1);
  constexpr int NCH = (K * CiPad + 31) / 32;
  constexpr int L2C = (CiPad == 8) ? 3 : 4;
  constexpr int DIV = (CiPad >= 32) ? (CiPad / 32) : 1;
  const int lane = threadIdx.x & 63;
  const int m = lane & 15, lb = (lane >> 4) * 8;
  if (gw == 0) {  // zero pad row of output (read via idx==nin next layer)
    for (int c = lane; c < Co; c += 64)
      L.fout[(size_t)L.nout * Co + c] = (_Float16)0.f;
  }
  const int ntile = ((L.nout + 15) >> 4) * CB;
  for (int it = gw; it < ntile; it += GW) {
    const int rt = it / CB, cb = it % CB;
    const int i0 = rt * 16;
    const int row = i0 + m;
    const bool rOK = row < L.nout;
    const int ct0 = cb * NTW;
    floatx4 acc[NTW];
#pragma unroll
    for (int n = 0; n < NTW; ++n) { floatx4 z = {0, 0, 0, 0}; acc[n] = z; }

    if constexpr (CiPad >= 32) {
      constexpr int NC = K * DIV;
      constexpr int DA = NC < 8 ? NC : 8;
      constexpr int DB = NC < 2 ? NC : 2;
      int idx[K];
#pragma unroll
      for (int q = 0; q < K; ++q) {
        int jj = rOK ? L.tbl[(size_t)q * L.nout + row] : -1;
        idx[q] = (jj < 0) ? L.nin : jj;
      }
      half8 ap[DA]; half8 bq[DB][NTW];
#pragma unroll
      for (int d = 0; d < DA; ++d)
        ap[d] = *(const half8*)(L.fin + (size_t)idx[d / DIV] * CiPad + (d % DIV) * 32 + lb);
#pragma unroll
      for (int d = 0; d < DB; ++d) {
        int ch = (d / DIV) * DIV + (d % DIV);
#pragma unroll
        for (int n = 0; n < NTW; ++n)
          bq[d][n] = *(const half8*)(L.bp + ((size_t)ch * NT * 64 + lane) * 8 +
                                     (size_t)(ct0 + n) * 512);
      }
#pragma unroll
      for (int ii = 0; ii < NC; ++ii) {
        half8 a = ap[ii % DA];
        half8 bt[NTW];
#pragma unroll
        for (int n = 0; n < NTW; ++n) bt[n] = bq[ii % DB][n];
        if (ii + DA < NC) {
          int nx = ii + DA;
          ap[ii % DA] = *(const half8*)(L.fin + (size_t)idx[nx / DIV] * CiPad +
                                        (nx % DIV) * 32 + lb);
        }
        if (ii + DB < NC) {
          int nx = ii + DB;
#pragma unroll
          for (int n = 0; n < NTW; ++n)
            bq[ii % DB][n] = *(const half8*)(L.bp + ((size_t)nx * NT * 64 + lane) * 8 +
                                             (size_t)(ct0 + n) * 512);
        }
#pragma unroll
        for (int n = 0; n < NTW; ++n)
          acc[n] = __builtin_amdgcn_mfma_f32_16x16x32_f16(a, bt[n], acc[n], 0, 0, 0);
      }
    } else {
      constexpr int NCW = NCH;
      constexpr int DA = NCW < 8 ? NCW : 8;
      constexpr int DB = NCW < 2 ? NCW : 2;
      int idx[NCW];
#pragma unroll
      for (int q = 0; q < NCW; ++q) {
        int ko = (q * 32 + lb) >> L2C;
        int jj = (rOK && ko < K) ? L.tbl[(size_t)ko * L.nout + row] : -1;
        idx[q] = (jj < 0) ? L.nin : jj;
      }
      half8 ap[DA]; half8 bq[DB][NTW];
#pragma unroll
      for (int d = 0; d < DA; ++d)
        ap[d] = *(const half8*)(L.fin + (size_t)idx[d] * CiPad + ((d * 32 + lb) & (CiPad - 1)));
#pragma unroll
      for (int d = 0; d < DB; ++d) {
#pragma unroll
        for (int n = 0; n < NTW; ++n)
          bq[d][n] = *(const half8*)(L.bp + ((size_t)d * NT * 64 + lane) * 8 +
                                     (size_t)(ct0 + n) * 512);
      }
#pragma unroll
      for (int ii = 0; ii < NCW; ++ii) {
        half8 a = ap[ii % DA];
        half8 bt[NTW];
#pragma unroll
        for (int n = 0; n < NTW; ++n) bt[n] = bq[ii % DB][n];
        if (ii + DA < NCW) {
          int nx = ii + DA;
          ap[ii % DA] = *(const half8*)(L.fin + (size_t)idx[nx] * CiPad +
                                        ((nx * 32 + lb) & (CiPad - 1)));
        }
        if (ii + DB < NCW) {
          int nx = ii + DB;
#pragma unroll
          for (int n = 0; n < NTW; ++n)
            bq[ii % DB][n] = *(const half8*)(L.bp + ((size_t)nx * NT * 64 + lane) * 8 +
                                             (size_t)(ct0 + n) * 512);
        }
#pragma unroll
        for (int n = 0; n < NTW; ++n)
          acc[n] = __builtin_amdgcn_mfma_f32_16x16x32_f16(a, bt[n], acc[n], 0, 0, 0);
      }
    }

    const int rl = (lane >> 4) * 4;
#pragma unroll
    for (int n = 0; n < NTW; ++n) {
      int col = (ct0 + n) * 16 + m;
      float s_ = L.sc[col], b_ = L.bi[col];
#pragma unroll
      for (int r = 0; r < 4; ++r) {
        int orow = i0 + rl + r;
        if (orow < L.nout)
          L.fout[(size_t)orow * Co + col] = (_Float16)fmaxf(fmaf(acc[n][r], s_, b_), 0.f);
      }
    }
  }
}

// per-wave 32x32x16 conv layer (KS=1, no LDS), grid-strided over row tiles
template <int K, int CiPad, int Co, int CB>
__device__ void conv32_layer(const LCfg L, int gw, int GW) {
  constexpr int NT = Co / 32;
  constexpr int NTW = NT / CB;
  static_assert(NT % CB == 0 && NTW >= 1);
  constexpr int SUB = CiPad / 16;
  constexpr int NC = K * SUB;
  constexpr int DA = NC < 8 ? NC : 8;
  constexpr int DB = NC < 2 ? NC : 2;
  const int lane = threadIdx.x & 63;
  const int m = lane & 31, lb = (lane >> 5) * 8, h = lane >> 5;
  if (gw == 0) {
    for (int c = lane; c < Co; c += 64)
      L.fout[(size_t)L.nout * Co + c] = (_Float16)0.f;
  }
  const int ntile = ((L.nout + 31) >> 5) * CB;
  for (int it = gw; it < ntile; it += GW) {
    const int rt = it / CB, cb = it % CB;
    const int i0 = rt * 32;
    const int row = i0 + m;
    const bool rOK = row < L.nout;
    const int ct0 = cb * NTW;
    floatx16 acc[NTW];
#pragma unroll
    for (int n = 0; n < NTW; ++n)
#pragma unroll
      for (int r = 0; r < 16; ++r) acc[n][r] = 0.f;

    int idx[K];
#pragma unroll
    for (int q = 0; q < K; ++q) {
      int jj = rOK ? L.tbl[(size_t)q * L.nout + row] : -1;
      idx[q] = (jj < 0) ? L.nin : jj;
    }
    half8 ap[DA]; half8 bq[DB][NTW];
#pragma unroll
    for (int d = 0; d < DA; ++d)
      ap[d] = *(const half8*)(L.fin + (size_t)idx[d / SUB] * CiPad + (d % SUB) * 16 + lb);
#pragma unroll
    for (int d = 0; d < DB; ++d) {
#pragma unroll
      for (int n = 0; n < NTW; ++n)
        bq[d][n] = *(const half8*)(L.bp + (size_t)(d * NT + ct0 + n) * 512 + lane * 8);
    }
#pragma unroll
    for (int ii = 0; ii < NC; ++ii) {
      half8 a = ap[ii % DA];
      half8 bt[NTW];
#pragma unroll
      for (int n = 0; n < NTW; ++n) bt[n] = bq[ii % DB][n];
      if (ii + DA < NC) {
        int nx = ii + DA;
        ap[ii % DA] = *(const half8*)(L.fin + (size_t)idx[nx / SUB] * CiPad +
                                      (nx % SUB) * 16 + lb);
      }
      if (ii + DB < NC) {
        int nx = ii + DB;
#pragma unroll
        for (int n = 0; n < NTW; ++n)
          bq[ii % DB][n] = *(const half8*)(L.bp + (size_t)(nx * NT + ct0 + n) * 512 + lane * 8);
      }
#pragma unroll
      for (int n = 0; n < NTW; ++n)
        acc[n] = __builtin_amdgcn_mfma_f32_32x32x16_f16(a, bt[n], acc[n], 0, 0, 0);
    }

#pragma unroll
    for (int n = 0; n < NTW; ++n) {
      int col = (ct0 + n) * 32 + m;
      float s_ = L.sc[col], b_ = L.bi[col];
#pragma unroll
      for (int reg = 0; reg < 16; ++reg) {
        int orow = i0 + (reg & 3) + 8 * (reg >> 2) + 4 * h;
        if (orow < L.nout)
          L.fout[(size_t)orow * Co + col] = (_Float16)fmaxf(fmaf(acc[n][reg], s_, b_), 0.f);
      }
    }
  }
}

// grid = 256 blocks x 512 threads (8 waves). launch_bounds(512,2) => VGPR
// budget 256/lane (no spills; round-4's 64-VGPR cap spilled ~900MB scratch).
// 256 blocks <= 256 CUs, 8 waves x <=256 VGPR = 2 waves/SIMD => every block
// gets a CU => all co-resident => software barrier cannot deadlock.
__global__ __launch_bounds__(512, 2) void net_persistent(PK P) {
  const int nblk = P.nblk;
  // phase -1: rulebook inversion (grid-strided scatter)
  {
    const int nthr = gridDim.x * 512;
    for (int idx = blockIdx.x * 512 + threadIdx.x; idx < P.totFill; idx += nthr) {
#pragma unroll
      for (int l = 0; l < 8; ++l) {
        if (idx >= P.rb[l].start && idx < P.rb[l].end) {
          const RB rb = P.rb[l];
          int e = idx - rb.start;
          int o = rb.rout[e];
          if ((unsigned)o < (unsigned)rb.nout) {
            int k = e / rb.R;
            P.tblBase[rb.off + (size_t)k * rb.nout + o] = rb.rin[e];
          }
        }
      }
    }
  }
  gsync(P.bar + 0, nblk);
  const int gw = blockIdx.x * 8 + (threadIdx.x >> 6);
  const int GW = gridDim.x * 8;
  conv16_layer<27, 8, 16, 1>(P.L[0], gw, GW);   gsync(P.bar + 1, nblk);
  conv16_layer<27, 16, 16, 1>(P.L[1], gw, GW);  gsync(P.bar + 2, nblk);
  conv16_layer<27, 16, 32, 1>(P.L[2], gw, GW);  gsync(P.bar + 3, nblk);
  conv32_layer<27, 32, 32, 1>(P.L[3], gw, GW);  gsync(P.bar + 4, nblk);
  conv32_layer<27, 32, 32, 1>(P.L[4], gw, GW);  gsync(P.bar + 5, nblk);
  conv32_layer<27, 32, 64, 2>(P.L[5], gw, GW);  gsync(P.bar + 6, nblk);
  conv32_layer<27, 64, 64, 2>(P.L[6], gw, GW);  gsync(P.bar + 7, nblk);
  conv32_layer<27, 64, 64, 2>(P.L[7], gw, GW);  gsync(P.bar + 8, nblk);
  conv32_layer<27, 64, 64, 2>(P.L[8], gw, GW);  gsync(P.bar + 9, nblk);
  conv32_layer<27, 64, 64, 2>(P.L[9], gw, GW);  gsync(P.bar + 10, nblk);
  conv32_layer<27, 64, 64, 2>(P.L[10], gw, GW); gsync(P.bar + 11, nblk);
  conv16_layer<3, 64, 128, 4>(P.L[11], gw, GW); gsync(P.bar + 12, nblk);
  // segmax: batch nondecreasing; run-length local max then one atomic per run
  {
    const _Float16* x = (const _Float16*)P.L[11].fout;
    int c = threadIdx.x & 127;
    int g = blockIdx.x * 4 + (threadIdx.x >> 7);
    int G = gridDim.x * 4;
    int per = (P.no + G - 1) / G;
    int r0 = g * per;
    int rend = min(P.no, r0 + per);
    float mx = 0.f;
    int cb = -1;
    for (int r = r0; r < rend; ++r) {
      int b = P.batch[r];
      if (b != cb) {
        if (cb >= 0) atomicMax((int*)P.dout + ((size_t)cb << 7) + c, __float_as_int(mx));
        cb = b; mx = 0.f;
      }
      mx = fmaxf(mx, (float)x[(size_t)r * 128 + c]);
    }
    if (cb >= 0) atomicMax((int*)P.dout + ((size_t)cb << 7) + c, __float_as_int(mx));
  }
}

extern "C" void kernel_launch(void* const* d_in, const int* in_sizes, int n_in,
                              void* d_out, int out_size, void* d_ws, size_t ws_size,
                              hipStream_t stream) {
  auto I = [&](int idx) { return (const int*)d_in[idx]; };
  auto F = [&](int idx) { return (const float*)d_in[idx]; };

  const int N0  = in_sizes[1];
  const int R1  = in_sizes[3] / 27;
  const int R2s = in_sizes[5] / 27;
  const int n2  = in_sizes[7];
  const int R2  = in_sizes[8] / 27;
  const int R3s = in_sizes[10] / 27;
  const int n3  = in_sizes[12];
  const int R3  = in_sizes[13] / 27;
  const int R4s = in_sizes[15] / 27;
  const int n4  = in_sizes[17];
  const int R4  = in_sizes[18] / 27;
  const int Ro  = in_sizes[20] / 3;
  const int no  = in_sizes[22];

  const int wIdx[12] = {23, 26, 29, 32, 35, 38, 41, 44, 47, 50, 53, 56};
  const int Ks[12]   = {27, 27, 27, 27, 27, 27, 27, 27, 27, 27, 27, 3};
  const int Cis[12]  = {4, 16, 16, 32, 32, 32, 64, 64, 64, 64, 64, 64};
  const int Cos[12]  = {16, 16, 32, 32, 32, 64, 64, 64, 64, 64, 64, 128};
  const int P32[12]  = {0, 0, 0, 1, 1, 1, 1, 1, 1, 1, 1, 0};
  WPs P;
  int wtot = 0;
  int bpOff[12];
  for (int l = 0; l < 12; ++l) {
    int cip = Cis[l] < 8 ? 8 : Cis[l];
    int sz;
    if (P32[l]) sz = Ks[l] * (cip / 16) * (Cos[l] / 32) * 512;
    else        sz = ((Ks[l] * cip + 31) / 32) * (Cos[l] / 16) * 512;
    P.d[l].W = F(wIdx[l]);
    P.d[l].K = Ks[l]; P.d[l].Ci = Cis[l]; P.d[l].CiPad = cip; P.d[l].Co = Cos[l];
    P.d[l].start = wtot; P.d[l].end = wtot + sz; P.d[l].off = wtot; P.d[l].p32 = P32[l];
    bpOff[l] = wtot;
    wtot += sz;
  }

  PK K;
  const int rbRin[8]  = {3, 5, 8, 10, 13, 15, 18, 20};
  const int rbRs[8]   = {R1, R2s, R2, R3s, R3, R4s, R4, Ro};
  const int rbKs[8]   = {27, 27, 27, 27, 27, 27, 27, 3};
  const int rbNout[8] = {N0, n2, n2, n3, n3, n4, n4, no};
  size_t tblOff[8];
  size_t totTbl = 0;
  int totFill = 0;
  for (int l = 0; l < 8; ++l) {
    tblOff[l] = totTbl;
    totTbl += (size_t)rbNout[l] * rbKs[l];
    K.rb[l].rin = I(rbRin[l]);
    K.rb[l].rout = I(rbRin[l] + 1);
    K.rb[l].K = rbKs[l]; K.rb[l].R = rbRs[l]; K.rb[l].nout = rbNout[l];
    K.rb[l].start = totFill;
    totFill += rbKs[l] * rbRs[l];
    K.rb[l].end = totFill;
    K.rb[l].off = (int)tblOff[l];
  }
  K.totFill = totFill;

  size_t S = (size_t)(N0 + 1) * 16;
  auto smax = [&](size_t v) { if (v > S) S = v; };
  smax((size_t)(n2 + 1) * 32);
  smax((size_t)(n3 + 1) * 64);
  smax((size_t)(n4 + 1) * 64);
  smax((size_t)(no + 1) * 128);
  S = (S + 7) & ~(size_t)7;

  _Float16* h = (_Float16*)d_ws;
  size_t off = 0;
  _Float16* f0 = h + off;   off += (size_t)(N0 + 1) * 8;
  _Float16* bufA = h + off; off += S;
  _Float16* bufB = h + off; off += S;
  _Float16* Bp = h + off;   off += (size_t)((wtot + 7) & ~7);
  int* tblBase = (int*)(h + off);
  int* bar = tblBase + totTbl;
  K.tblBase = tblBase;
  K.bar = bar;
  K.nblk = 256;

  // fused prep: feat + zero d_out + tbl init (-1) + barrier zero + weights
  P.vox = F(0); P.vnp = I(1); P.f0 = f0;
  P.featTot = (N0 + 1) * 8; P.N0 = N0;
  P.dout = (float*)d_out; P.outTot = out_size;
  P.tbl = tblBase; P.tblTot = (int)totTbl;
  P.bar = bar;
  int prepTot = P.featTot + P.outTot + P.tblTot + 16 + wtot;
  prep_all<<<cdiv_i(prepTot, 256), 256, 0, stream>>>(P, Bp, prepTot);

  // layer wiring (ping-pong f0 -> A -> B -> ...)
  const int l2rb[12] = {0, 0, 1, 2, 2, 3, 4, 4, 5, 6, 6, 7};
  const int louts[12] = {N0, N0, n2, n2, n2, n3, n3, n3, n4, n4, n4, no};
  const int lins[12]  = {N0, N0, N0, n2, n2, n2, n3, n3, n3, n4, n4, n4};
  _Float16* bufs[13];
  bufs[0] = f0;
  for (int l = 0; l < 12; ++l) bufs[l + 1] = (l & 1) ? bufB : bufA;
  // f0 -> bufA -> bufB -> bufA -> ... (bufs[1]=A, bufs[2]=B, ...)
  for (int l = 0; l < 12; ++l) {
    K.L[l].fin  = bufs[l];
    K.L[l].fout = bufs[l + 1];
    K.L[l].bp   = Bp + bpOff[l];
    K.L[l].tbl  = tblBase + tblOff[l2rb[l]];
    K.L[l].sc   = F(wIdx[l] + 1);
    K.L[l].bi   = F(wIdx[l] + 2);
    K.L[l].nout = louts[l];
    K.L[l].nin  = lins[l];
  }
  K.batch = I(22); K.no = no; K.dout = (float*)d_out;

  net_persistent<<<256, 512, 0, stream>>>(K);
}

// Round 6
// 817.434 us; speedup vs baseline: 2.6086x; 1.0008x over previous
//
#include <hip/hip_runtime.h>
#include <cstddef>
#include <cstdint>

typedef _Float16 half8 __attribute__((ext_vector_type(8)));
typedef float floatx4 __attribute__((ext_vector_type(4)));
typedef float floatx16 __attribute__((ext_vector_type(16)));

static inline int cdiv_i(int a, int b) { return (a + b - 1) / b; }

// ---- rulebook descriptor: tbl[k*nout + o] = in (TRANSPOSED, -1 = absent)
struct RB { const int* rin; const int* rout; int K, R, nout, start, end, off; };

// ---- fused prep: feat (f16 pad8) + zero d_out + tbl init (-1) + barrier
//      counters (0) + weight pack
struct WP { const float* W; int K, Ci, CiPad, Co, start, end, off, p32; };
struct WPs {
  WP d[12];
  const float* vox; const int* vnp; _Float16* f0; int featTot, N0;
  float* dout; int outTot;
  int* tbl; int tblTot;
  int* bar; // 16 ints, zeroed each replay (harness poisons d_ws)
};
__global__ void prep_all(WPs P, _Float16* __restrict__ Bp, int total) {
  int idx = blockIdx.x * blockDim.x + threadIdx.x;
  if (idx >= total) return;
  if (idx < P.featTot) {
    int i = idx >> 3, c = idx & 7;
    float v = 0.f;
    if (i < P.N0 && c < 4) {
      const float* p = P.vox + (size_t)i * 20 + c;
      v = (p[0] + p[4] + p[8] + p[12] + p[16]) / fmaxf((float)P.vnp[i], 1.f);
    }
    P.f0[idx] = (_Float16)v;
    return;
  }
  idx -= P.featTot;
  if (idx < P.outTot) { P.dout[idx] = 0.f; return; }
  idx -= P.outTot;
  if (idx < P.tblTot) { P.tbl[idx] = -1; return; }
  idx -= P.tblTot;
  if (idx < 16) { P.bar[idx] = 0; return; }
  int widx = idx - 16;
#pragma unroll
  for (int l = 0; l < 12; ++l) {
    if (widx >= P.d[l].start && widx < P.d[l].end) {
      const WP w = P.d[l];
      int e = widx - w.start;
      int j = e & 7;
      int lane = (e >> 3) & 63;
      int rest = e >> 9;
      float v;
      if (w.p32) {
        int NT = w.Co >> 5;
        int t = rest % NT, ch = rest / NT;
        int SUB = w.CiPad >> 4;
        int ko = ch / SUB, s = ch % SUB;
        int ci = s * 16 + ((lane >> 5) << 3) + j;
        int col = t * 32 + (lane & 31);
        v = w.W[((size_t)ko * w.Ci + ci) * w.Co + col];
      } else {
        int NT = w.Co >> 4;
        int t = rest % NT, ch = rest / NT;
        int kk = ch * 32 + ((lane >> 4) << 3) + j;
        int k = kk / w.CiPad, ci = kk % w.CiPad;
        int n = t * 16 + (lane & 15);
        v = (k < w.K && ci < w.Ci) ? w.W[((size_t)k * w.Ci + ci) * w.Co + n] : 0.f;
      }
      Bp[w.off + e] = (_Float16)v;
    }
  }
}

// ---- persistent-kernel pieces --------------------------------------------

struct LCfg {
  const _Float16* fin; _Float16* fout; const _Float16* bp;
  const int* tbl; const float* sc; const float* bi; int nout, nin;
};

struct PK {
  RB rb[8]; int totFill; int* tblBase;
  LCfg L[12];
  const int* batch; int no; float* dout;
  int* bar; int nblk;
};

// one-shot grid barrier, counters pre-zeroed by prep_all each replay.
// Round-3 lesson: fence ONCE per crossing, spin RELAXED (per-poll ACQUIRE
// serialized at ~2.5x cost). Round-4/5 lesson: excess HBM traffic was VGPR
// spill scratch; launch_bounds alone lets the backend shrink VGPR to 128
// chasing occupancy our 1-block/CU grid can never use.
__device__ __forceinline__ void gsync(int* c, int nblk) {
  __syncthreads();
  if (threadIdx.x == 0) {
    __builtin_amdgcn_fence(__ATOMIC_RELEASE, "agent");  // one wbl2: publish our writes
    __hip_atomic_fetch_add(c, 1, __ATOMIC_RELAXED, __HIP_MEMORY_SCOPE_AGENT);
    while (__hip_atomic_load(c, __ATOMIC_RELAXED, __HIP_MEMORY_SCOPE_AGENT) < nblk)
      __builtin_amdgcn_s_sleep(8);                      // relaxed poll: no cache ops
    __builtin_amdgcn_fence(__ATOMIC_ACQUIRE, "agent");  // one inv: see others' writes
  }
  __syncthreads();
}

// per-wave 16x16x32 conv layer (KS=1, no LDS), grid-strided over row tiles
template <int K, int CiPad, int Co, int CB>
__device__ void conv16_layer(const LCfg L, int gw, int GW) {
  constexpr int NT = Co / 16;
  constexpr int NTW = NT / CB;
  static_assert(NT % CB == 0 && NTW >= 1);
  constexpr int NCH = (K * CiPad + 31) / 32;
  constexpr int L2C = (CiPad == 8) ? 3 : 4;
  constexpr int DIV = (CiPad >= 32) ? (CiPad / 32) : 1;
  const int lane = threadIdx.x & 63;
  const int m = lane & 15, lb = (lane >> 4) * 8;
  if (gw == 0) {  // zero pad row of output (read via idx==nin next layer)
    for (int c = lane; c < Co; c += 64)
      L.fout[(size_t)L.nout * Co + c] = (_Float16)0.f;
  }
  const int ntile = ((L.nout + 15) >> 4) * CB;
  for (int it = gw; it < ntile; it += GW) {
    const int rt = it / CB, cb = it % CB;
    const int i0 = rt * 16;
    const int row = i0 + m;
    const bool rOK = row < L.nout;
    const int ct0 = cb * NTW;
    floatx4 acc[NTW];
#pragma unroll
    for (int n = 0; n < NTW; ++n) { floatx4 z = {0, 0, 0, 0}; acc[n] = z; }

    if constexpr (CiPad >= 32) {
      constexpr int NC = K * DIV;
      constexpr int DA = NC < 8 ? NC : 8;
      constexpr int DB = NC < 2 ? NC : 2;
      int idx[K];
#pragma unroll
      for (int q = 0; q < K; ++q) {
        int jj = rOK ? L.tbl[(size_t)q * L.nout + row] : -1;
        idx[q] = (jj < 0) ? L.nin : jj;
      }
      half8 ap[DA]; half8 bq[DB][NTW];
#pragma unroll
      for (int d = 0; d < DA; ++d)
        ap[d] = *(const half8*)(L.fin + (size_t)idx[d / DIV] * CiPad + (d % DIV) * 32 + lb);
#pragma unroll
      for (int d = 0; d < DB; ++d) {
        int ch = (d / DIV) * DIV + (d % DIV);
#pragma unroll
        for (int n = 0; n < NTW; ++n)
          bq[d][n] = *(const half8*)(L.bp + ((size_t)ch * NT * 64 + lane) * 8 +
                                     (size_t)(ct0 + n) * 512);
      }
#pragma unroll
      for (int ii = 0; ii < NC; ++ii) {
        half8 a = ap[ii % DA];
        half8 bt[NTW];
#pragma unroll
        for (int n = 0; n < NTW; ++n) bt[n] = bq[ii % DB][n];
        if (ii + DA < NC) {
          int nx = ii + DA;
          ap[ii % DA] = *(const half8*)(L.fin + (size_t)idx[nx / DIV] * CiPad +
                                        (nx % DIV) * 32 + lb);
        }
        if (ii + DB < NC) {
          int nx = ii + DB;
#pragma unroll
          for (int n = 0; n < NTW; ++n)
            bq[ii % DB][n] = *(const half8*)(L.bp + ((size_t)nx * NT * 64 + lane) * 8 +
                                             (size_t)(ct0 + n) * 512);
        }
#pragma unroll
        for (int n = 0; n < NTW; ++n)
          acc[n] = __builtin_amdgcn_mfma_f32_16x16x32_f16(a, bt[n], acc[n], 0, 0, 0);
      }
    } else {
      constexpr int NCW = NCH;
      constexpr int DA = NCW < 8 ? NCW : 8;
      constexpr int DB = NCW < 2 ? NCW : 2;
      int idx[NCW];
#pragma unroll
      for (int q = 0; q < NCW; ++q) {
        int ko = (q * 32 + lb) >> L2C;
        int jj = (rOK && ko < K) ? L.tbl[(size_t)ko * L.nout + row] : -1;
        idx[q] = (jj < 0) ? L.nin : jj;
      }
      half8 ap[DA]; half8 bq[DB][NTW];
#pragma unroll
      for (int d = 0; d < DA; ++d)
        ap[d] = *(const half8*)(L.fin + (size_t)idx[d] * CiPad + ((d * 32 + lb) & (CiPad - 1)));
#pragma unroll
      for (int d = 0; d < DB; ++d) {
#pragma unroll
        for (int n = 0; n < NTW; ++n)
          bq[d][n] = *(const half8*)(L.bp + ((size_t)d * NT * 64 + lane) * 8 +
                                     (size_t)(ct0 + n) * 512);
      }
#pragma unroll
      for (int ii = 0; ii < NCW; ++ii) {
        half8 a = ap[ii % DA];
        half8 bt[NTW];
#pragma unroll
        for (int n = 0; n < NTW; ++n) bt[n] = bq[ii % DB][n];
        if (ii + DA < NCW) {
          int nx = ii + DA;
          ap[ii % DA] = *(const half8*)(L.fin + (size_t)idx[nx] * CiPad +
                                        ((nx * 32 + lb) & (CiPad - 1)));
        }
        if (ii + DB < NCW) {
          int nx = ii + DB;
#pragma unroll
          for (int n = 0; n < NTW; ++n)
            bq[ii % DB][n] = *(const half8*)(L.bp + ((size_t)nx * NT * 64 + lane) * 8 +
                                             (size_t)(ct0 + n) * 512);
        }
#pragma unroll
        for (int n = 0; n < NTW; ++n)
          acc[n] = __builtin_amdgcn_mfma_f32_16x16x32_f16(a, bt[n], acc[n], 0, 0, 0);
      }
    }

    const int rl = (lane >> 4) * 4;
#pragma unroll
    for (int n = 0; n < NTW; ++n) {
      int col = (ct0 + n) * 16 + m;
      float s_ = L.sc[col], b_ = L.bi[col];
#pragma unroll
      for (int r = 0; r < 4; ++r) {
        int orow = i0 + rl + r;
        if (orow < L.nout)
          L.fout[(size_t)orow * Co + col] = (_Float16)fmaxf(fmaf(acc[n][r], s_, b_), 0.f);
      }
    }
  }
}

// per-wave 32x32x16 conv layer (KS=1, no LDS), grid-strided over row tiles
template <int K, int CiPad, int Co, int CB>
__device__ void conv32_layer(const LCfg L, int gw, int GW) {
  constexpr int NT = Co / 32;
  constexpr int NTW = NT / CB;
  static_assert(NT % CB == 0 && NTW >= 1);
  constexpr int SUB = CiPad / 16;
  constexpr int NC = K * SUB;
  constexpr int DA = NC < 8 ? NC : 8;
  constexpr int DB = NC < 2 ? NC : 2;
  const int lane = threadIdx.x & 63;
  const int m = lane & 31, lb = (lane >> 5) * 8, h = lane >> 5;
  if (gw == 0) {
    for (int c = lane; c < Co; c += 64)
      L.fout[(size_t)L.nout * Co + c] = (_Float16)0.f;
  }
  const int ntile = ((L.nout + 31) >> 5) * CB;
  for (int it = gw; it < ntile; it += GW) {
    const int rt = it / CB, cb = it % CB;
    const int i0 = rt * 32;
    const int row = i0 + m;
    const bool rOK = row < L.nout;
    const int ct0 = cb * NTW;
    floatx16 acc[NTW];
#pragma unroll
    for (int n = 0; n < NTW; ++n)
#pragma unroll
      for (int r = 0; r < 16; ++r) acc[n][r] = 0.f;

    int idx[K];
#pragma unroll
    for (int q = 0; q < K; ++q) {
      int jj = rOK ? L.tbl[(size_t)q * L.nout + row] : -1;
      idx[q] = (jj < 0) ? L.nin : jj;
    }
    half8 ap[DA]; half8 bq[DB][NTW];
#pragma unroll
    for (int d = 0; d < DA; ++d)
      ap[d] = *(const half8*)(L.fin + (size_t)idx[d / SUB] * CiPad + (d % SUB) * 16 + lb);
#pragma unroll
    for (int d = 0; d < DB; ++d) {
#pragma unroll
      for (int n = 0; n < NTW; ++n)
        bq[d][n] = *(const half8*)(L.bp + (size_t)(d * NT + ct0 + n) * 512 + lane * 8);
    }
#pragma unroll
    for (int ii = 0; ii < NC; ++ii) {
      half8 a = ap[ii % DA];
      half8 bt[NTW];
#pragma unroll
      for (int n = 0; n < NTW; ++n) bt[n] = bq[ii % DB][n];
      if (ii + DA < NC) {
        int nx = ii + DA;
        ap[ii % DA] = *(const half8*)(L.fin + (size_t)idx[nx / SUB] * CiPad +
                                      (nx % SUB) * 16 + lb);
      }
      if (ii + DB < NC) {
        int nx = ii + DB;
#pragma unroll
        for (int n = 0; n < NTW; ++n)
          bq[ii % DB][n] = *(const half8*)(L.bp + (size_t)(nx * NT + ct0 + n) * 512 + lane * 8);
      }
#pragma unroll
      for (int n = 0; n < NTW; ++n)
        acc[n] = __builtin_amdgcn_mfma_f32_32x32x16_f16(a, bt[n], acc[n], 0, 0, 0);
    }

#pragma unroll
    for (int n = 0; n < NTW; ++n) {
      int col = (ct0 + n) * 32 + m;
      float s_ = L.sc[col], b_ = L.bi[col];
#pragma unroll
      for (int reg = 0; reg < 16; ++reg) {
        int orow = i0 + (reg & 3) + 8 * (reg >> 2) + 4 * h;
        if (orow < L.nout)
          L.fout[(size_t)orow * Co + col] = (_Float16)fmaxf(fmaf(acc[n][reg], s_, b_), 0.f);
      }
    }
  }
}

// grid = 256 blocks x 512 threads (8 waves, 2/SIMD). waves_per_eu(2,2) pins
// the VGPR budget at 256/lane: round-5 showed launch_bounds alone lets the
// backend shrink to 128 VGPR (chasing occupancy a 1-block/CU grid can't use)
// and spill ~250MB of scratch. 256 blocks <= 256 CUs, VGPR<=256, LDS=0 =>
// all blocks co-resident => software barrier cannot deadlock.
__global__ __attribute__((amdgpu_flat_work_group_size(512, 512),
                          amdgpu_waves_per_eu(2, 2)))
void net_persistent(PK P) {
  const int nblk = P.nblk;
  // phase -1: rulebook inversion (grid-strided scatter)
  {
    const int nthr = gridDim.x * 512;
    for (int idx = blockIdx.x * 512 + threadIdx.x; idx < P.totFill; idx += nthr) {
#pragma unroll
      for (int l = 0; l < 8; ++l) {
        if (idx >= P.rb[l].start && idx < P.rb[l].end) {
          const RB rb = P.rb[l];
          int e = idx - rb.start;
          int o = rb.rout[e];
          if ((unsigned)o < (unsigned)rb.nout) {
            int k = e / rb.R;
            P.tblBase[rb.off + (size_t)k * rb.nout + o] = rb.rin[e];
          }
        }
      }
    }
  }
  gsync(P.bar + 0, nblk);
  const int gw = blockIdx.x * 8 + (threadIdx.x >> 6);
  const int GW = gridDim.x * 8;
  conv16_layer<27, 8, 16, 1>(P.L[0], gw, GW);   gsync(P.bar + 1, nblk);
  conv16_layer<27, 16, 16, 1>(P.L[1], gw, GW);  gsync(P.bar + 2, nblk);
  conv16_layer<27, 16, 32, 1>(P.L[2], gw, GW);  gsync(P.bar + 3, nblk);
  conv32_layer<27, 32, 32, 1>(P.L[3], gw, GW);  gsync(P.bar + 4, nblk);
  conv32_layer<27, 32, 32, 1>(P.L[4], gw, GW);  gsync(P.bar + 5, nblk);
  conv32_layer<27, 32, 64, 2>(P.L[5], gw, GW);  gsync(P.bar + 6, nblk);
  conv32_layer<27, 64, 64, 2>(P.L[6], gw, GW);  gsync(P.bar + 7, nblk);
  conv32_layer<27, 64, 64, 2>(P.L[7], gw, GW);  gsync(P.bar + 8, nblk);
  conv32_layer<27, 64, 64, 2>(P.L[8], gw, GW);  gsync(P.bar + 9, nblk);
  conv32_layer<27, 64, 64, 2>(P.L[9], gw, GW);  gsync(P.bar + 10, nblk);
  conv32_layer<27, 64, 64, 2>(P.L[10], gw, GW); gsync(P.bar + 11, nblk);
  conv16_layer<3, 64, 128, 4>(P.L[11], gw, GW); gsync(P.bar + 12, nblk);
  // segmax: batch nondecreasing; run-length local max then one atomic per run
  {
    const _Float16* x = (const _Float16*)P.L[11].fout;
    int c = threadIdx.x & 127;
    int g = blockIdx.x * 4 + (threadIdx.x >> 7);
    int G = gridDim.x * 4;
    int per = (P.no + G - 1) / G;
    int r0 = g * per;
    int rend = min(P.no, r0 + per);
    float mx = 0.f;
    int cb = -1;
    for (int r = r0; r < rend; ++r) {
      int b = P.batch[r];
      if (b != cb) {
        if (cb >= 0) atomicMax((int*)P.dout + ((size_t)cb << 7) + c, __float_as_int(mx));
        cb = b; mx = 0.f;
      }
      mx = fmaxf(mx, (float)x[(size_t)r * 128 + c]);
    }
    if (cb >= 0) atomicMax((int*)P.dout + ((size_t)cb << 7) + c, __float_as_int(mx));
  }
}

extern "C" void kernel_launch(void* const* d_in, const int* in_sizes, int n_in,
                              void* d_out, int out_size, void* d_ws, size_t ws_size,
                              hipStream_t stream) {
  auto I = [&](int idx) { return (const int*)d_in[idx]; };
  auto F = [&](int idx) { return (const float*)d_in[idx]; };

  const int N0  = in_sizes[1];
  const int R1  = in_sizes[3] / 27;
  const int R2s = in_sizes[5] / 27;
  const int n2  = in_sizes[7];
  const int R2  = in_sizes[8] / 27;
  const int R3s = in_sizes[10] / 27;
  const int n3  = in_sizes[12];
  const int R3  = in_sizes[13] / 27;
  const int R4s = in_sizes[15] / 27;
  const int n4  = in_sizes[17];
  const int R4  = in_sizes[18] / 27;
  const int Ro  = in_sizes[20] / 3;
  const int no  = in_sizes[22];

  const int wIdx[12] = {23, 26, 29, 32, 35, 38, 41, 44, 47, 50, 53, 56};
  const int Ks[12]   = {27, 27, 27, 27, 27, 27, 27, 27, 27, 27, 27, 3};
  const int Cis[12]  = {4, 16, 16, 32, 32, 32, 64, 64, 64, 64, 64, 64};
  const int Cos[12]  = {16, 16, 32, 32, 32, 64, 64, 64, 64, 64, 64, 128};
  const int P32[12]  = {0, 0, 0, 1, 1, 1, 1, 1, 1, 1, 1, 0};
  WPs P;
  int wtot = 0;
  int bpOff[12];
  for (int l = 0; l < 12; ++l) {
    int cip = Cis[l] < 8 ? 8 : Cis[l];
    int sz;
    if (P32[l]) sz = Ks[l] * (cip / 16) * (Cos[l] / 32) * 512;
    else        sz = ((Ks[l] * cip + 31) / 32) * (Cos[l] / 16) * 512;
    P.d[l].W = F(wIdx[l]);
    P.d[l].K = Ks[l]; P.d[l].Ci = Cis[l]; P.d[l].CiPad = cip; P.d[l].Co = Cos[l];
    P.d[l].start = wtot; P.d[l].end = wtot + sz; P.d[l].off = wtot; P.d[l].p32 = P32[l];
    bpOff[l] = wtot;
    wtot += sz;
  }

  PK K;
  const int rbRin[8]  = {3, 5, 8, 10, 13, 15, 18, 20};
  const int rbRs[8]   = {R1, R2s, R2, R3s, R3, R4s, R4, Ro};
  const int rbKs[8]   = {27, 27, 27, 27, 27, 27, 27, 3};
  const int rbNout[8] = {N0, n2, n2, n3, n3, n4, n4, no};
  size_t tblOff[8];
  size_t totTbl = 0;
  int totFill = 0;
  for (int l = 0; l < 8; ++l) {
    tblOff[l] = totTbl;
    totTbl += (size_t)rbNout[l] * rbKs[l];
    K.rb[l].rin = I(rbRin[l]);
    K.rb[l].rout = I(rbRin[l] + 1);
    K.rb[l].K = rbKs[l]; K.rb[l].R = rbRs[l]; K.rb[l].nout = rbNout[l];
    K.rb[l].start = totFill;
    totFill += rbKs[l] * rbRs[l];
    K.rb[l].end = totFill;
    K.rb[l].off = (int)tblOff[l];
  }
  K.totFill = totFill;

  size_t S = (size_t)(N0 + 1) * 16;
  auto smax = [&](size_t v) { if (v > S) S = v; };
  smax((size_t)(n2 + 1) * 32);
  smax((size_t)(n3 + 1) * 64);
  smax((size_t)(n4 + 1) * 64);
  smax((size_t)(no + 1) * 128);
  S = (S + 7) & ~(size_t)7;

  _Float16* h = (_Float16*)d_ws;
  size_t off = 0;
  _Float16* f0 = h + off;   off += (size_t)(N0 + 1) * 8;
  _Float16* bufA = h + off; off += S;
  _Float16* bufB = h + off; off += S;
  _Float16* Bp = h + off;   off += (size_t)((wtot + 7) & ~7);
  int* tblBase = (int*)(h + off);
  int* bar = tblBase + totTbl;
  K.tblBase = tblBase;
  K.bar = bar;
  K.nblk = 256;

  // fused prep: feat + zero d_out + tbl init (-1) + barrier zero + weights
  P.vox = F(0); P.vnp = I(1); P.f0 = f0;
  P.featTot = (N0 + 1) * 8; P.N0 = N0;
  P.dout = (float*)d_out; P.outTot = out_size;
  P.tbl = tblBase; P.tblTot = (int)totTbl;
  P.bar = bar;
  int prepTot = P.featTot + P.outTot + P.tblTot + 16 + wtot;
  prep_all<<<cdiv_i(prepTot, 256), 256, 0, stream>>>(P, Bp, prepTot);

  // layer wiring (ping-pong f0 -> A -> B -> ...)
  const int l2rb[12] = {0, 0, 1, 2, 2, 3, 4, 4, 5, 6, 6, 7};
  const int louts[12] = {N0, N0, n2, n2, n2, n3, n3, n3, n4, n4, n4, no};
  const int lins[12]  = {N0, N0, N0, n2, n2, n2, n3, n3, n3, n4, n4, n4};
  _Float16* bufs[13];
  bufs[0] = f0;
  for (int l = 0; l < 12; ++l) bufs[l + 1] = (l & 1) ? bufB : bufA;
  // f0 -> bufA -> bufB -> bufA -> ... (bufs[1]=A, bufs[2]=B, ...)
  for (int l = 0; l < 12; ++l) {
    K.L[l].fin  = bufs[l];
    K.L[l].fout = bufs[l + 1];
    K.L[l].bp   = Bp + bpOff[l];
    K.L[l].tbl  = tblBase + tblOff[l2rb[l]];
    K.L[l].sc   = F(wIdx[l] + 1);
    K.L[l].bi   = F(wIdx[l] + 2);
    K.L[l].nout = louts[l];
    K.L[l].nin  = lins[l];
  }
  K.batch = I(22); K.no = no; K.dout = (float*)d_out;

  net_persistent<<<256, 512, 0, stream>>>(K);
}

// Round 7
// 620.872 us; speedup vs baseline: 3.4344x; 1.3166x over previous
//
#include <hip/hip_runtime.h>
#include <cstddef>
#include <cstdint>

typedef _Float16 half8 __attribute__((ext_vector_type(8)));
typedef float floatx4 __attribute__((ext_vector_type(4)));
typedef float floatx16 __attribute__((ext_vector_type(16)));

static inline int cdiv_i(int a, int b) { return (a + b - 1) / b; }

// ---- rulebook inversion, TRANSPOSED tables: tbl[k*nout + o] = in
struct RB { const int* rin; const int* rout; int K, R, nout, start, end, off; };
struct RBs { RB d[8]; };
__global__ void rb_fill_all(RBs P, int* __restrict__ tbl, int total) {
  int idx = blockIdx.x * blockDim.x + threadIdx.x;
  if (idx >= total) return;
#pragma unroll
  for (int l = 0; l < 8; ++l) {
    if (idx >= P.d[l].start && idx < P.d[l].end) {
      const RB rb = P.d[l];
      int e = idx - rb.start;
      int o = rb.rout[e];
      if ((unsigned)o < (unsigned)rb.nout) {
        int k = e / rb.R;
        tbl[rb.off + (size_t)k * rb.nout + o] = rb.rin[e];
      }
    }
  }
}

// ---- fused prep: feat (f16 pad8) + zero d_out + tbl init (-1) + bar(0)
//      + weight pack
struct WP { const float* W; int K, Ci, CiPad, Co, start, end, off, p32; };
struct WPs {
  WP d[12];
  const float* vox; const int* vnp; _Float16* f0; int featTot, N0;
  float* dout; int outTot;
  int* tbl; int tblTot;
  int* bar;
};
__global__ void prep_all(WPs P, _Float16* __restrict__ Bp, int total) {
  int idx = blockIdx.x * blockDim.x + threadIdx.x;
  if (idx >= total) return;
  if (idx < P.featTot) {
    int i = idx >> 3, c = idx & 7;
    float v = 0.f;
    if (i < P.N0 && c < 4) {
      const float* p = P.vox + (size_t)i * 20 + c;
      v = (p[0] + p[4] + p[8] + p[12] + p[16]) / fmaxf((float)P.vnp[i], 1.f);
    }
    P.f0[idx] = (_Float16)v;
    return;
  }
  idx -= P.featTot;
  if (idx < P.outTot) { P.dout[idx] = 0.f; return; }
  idx -= P.outTot;
  if (idx < P.tblTot) { P.tbl[idx] = -1; return; }
  idx -= P.tblTot;
  if (idx < 16) { P.bar[idx] = 0; return; }
  int widx = idx - 16;
#pragma unroll
  for (int l = 0; l < 12; ++l) {
    if (widx >= P.d[l].start && widx < P.d[l].end) {
      const WP w = P.d[l];
      int e = widx - w.start;
      int j = e & 7;
      int lane = (e >> 3) & 63;
      int rest = e >> 9;
      float v;
      if (w.p32) {
        int NT = w.Co >> 5;
        int t = rest % NT, ch = rest / NT;
        int SUB = w.CiPad >> 4;
        int ko = ch / SUB, s = ch % SUB;
        int ci = s * 16 + ((lane >> 5) << 3) + j;
        int col = t * 32 + (lane & 31);
        v = w.W[((size_t)ko * w.Ci + ci) * w.Co + col];
      } else {
        int NT = w.Co >> 4;
        int t = rest % NT, ch = rest / NT;
        int kk = ch * 32 + ((lane >> 4) << 3) + j;
        int k = kk / w.CiPad, ci = kk % w.CiPad;
        int n = t * 16 + (lane & 15);
        v = (k < w.K && ci < w.Ci) ? w.W[((size_t)k * w.Ci + ci) * w.Co + n] : 0.f;
      }
      Bp[w.off + e] = (_Float16)v;
    }
  }
}

// ======== multi-kernel 16x16x32 path (round-0 proven, big layers) ========
template <int K, int CiPad, int Co, int KS, int CG, int CBLK>
__global__ __launch_bounds__(256) void conv_mfma(
    const _Float16* __restrict__ feat, const _Float16* __restrict__ Bp,
    const int* __restrict__ tbl, const float* __restrict__ sc,
    const float* __restrict__ bi, _Float16* __restrict__ out,
    int nout, int nin) {
  constexpr int NT = Co / 16;
  constexpr int NTE = NT / CBLK;
  constexpr int NTW = NTE / CG;
  constexpr int RG = 4 / (KS * CG);
  static_assert(KS * CG * RG == 4 && RG >= 1 && NT % CBLK == 0 && NTE % CG == 0);
  constexpr int NCH = (K * CiPad + 31) / 32;
  constexpr int L2C = (CiPad == 8) ? 3 : 4;
  constexpr int DIV = (CiPad >= 32) ? (CiPad / 32) : 1;
  constexpr int CoP = NTE * 16 + 4;

  __shared__ float red[(KS > 1) ? (KS - 1) * RG * 16 * CoP : 1];

  if (blockIdx.x == 0 && threadIdx.x < Co)
    out[(size_t)nout * Co + threadIdx.x] = (_Float16)0.f;

  int id = blockIdx.x;
  { int nb = gridDim.x, nb8 = (nb >> 3) << 3;
    if (id < nb8) { int per = nb >> 3; id = (id & 7) * per + (id >> 3); } }
  const int rt = id / CBLK, cb = id % CBLK;
  const int wave = threadIdx.x >> 6, lane = threadIdx.x & 63;
  const int ks = wave % KS;
  const int cg = (wave / KS) % CG;
  const int rowg = wave / (KS * CG);
  const int m = lane & 15, lb = (lane >> 4) * 8;
  const int i0 = (rt * RG + rowg) * 16;
  if constexpr (KS == 1) { if (i0 >= nout) return; }
  const int row = i0 + m;
  const bool rOK = row < nout;
  const int ct0 = cb * NTE + cg * NTW;

  floatx4 acc[NTW];
#pragma unroll
  for (int n = 0; n < NTW; ++n) { floatx4 z = {0,0,0,0}; acc[n] = z; }

  if constexpr (CiPad >= 32) {
    constexpr int NKW = (K + KS - 1) / KS;
    constexpr int NC = NKW * DIV;
    constexpr int DA = NC < 8 ? NC : 8;
    constexpr int DB = NC < 2 ? NC : 2;
    int idx[NKW];
#pragma unroll
    for (int q = 0; q < NKW; ++q) {
      int k = ks * NKW + q;
      int jj = (rOK && k < K) ? tbl[(size_t)k * nout + row] : -1;
      idx[q] = (jj < 0) ? nin : jj;
    }
    half8 ap[DA]; half8 bq[DB][NTW];
#pragma unroll
    for (int d = 0; d < DA; ++d)
      ap[d] = *(const half8*)(feat + (size_t)idx[d / DIV] * CiPad + (d % DIV) * 32 + lb);
#pragma unroll
    for (int d = 0; d < DB; ++d) {
      int k = ks * NKW + d / DIV;
      int ch = ((k < K) ? k : (K - 1)) * DIV + (d % DIV);
#pragma unroll
      for (int n = 0; n < NTW; ++n)
        bq[d][n] = *(const half8*)(Bp + ((size_t)ch * NT * 64 + lane) * 8 +
                                   (size_t)(ct0 + n) * 512);
    }
#pragma unroll
    for (int ii = 0; ii < NC; ++ii) {
      half8 a = ap[ii % DA];
      half8 bt[NTW];
#pragma unroll
      for (int n = 0; n < NTW; ++n) bt[n] = bq[ii % DB][n];
      if (ii + DA < NC) {
        int nx = ii + DA;
        ap[ii % DA] = *(const half8*)(feat + (size_t)idx[nx / DIV] * CiPad +
                                      (nx % DIV) * 32 + lb);
      }
      if (ii + DB < NC) {
        int nx = ii + DB;
        int k = ks * NKW + nx / DIV;
        int ch = ((k < K) ? k : (K - 1)) * DIV + (nx % DIV);
#pragma unroll
        for (int n = 0; n < NTW; ++n)
          bq[ii % DB][n] = *(const half8*)(Bp + ((size_t)ch * NT * 64 + lane) * 8 +
                                           (size_t)(ct0 + n) * 512);
      }
#pragma unroll
      for (int n = 0; n < NTW; ++n)
        acc[n] = __builtin_amdgcn_mfma_f32_16x16x32_f16(a, bt[n], acc[n], 0, 0, 0);
    }
  } else {
    constexpr int NCW = (NCH + KS - 1) / KS;
    constexpr int DA = NCW < 8 ? NCW : 8;
    constexpr int DB = NCW < 2 ? NCW : 2;
    int idx[NCW];
#pragma unroll
    for (int q = 0; q < NCW; ++q) {
      int ch = ks * NCW + q;
      int ko = (ch * 32 + lb) >> L2C;
      int jj = (rOK && ko < K && ch < NCH) ? tbl[(size_t)ko * nout + row] : -1;
      idx[q] = (jj < 0) ? nin : jj;
    }
    half8 ap[DA]; half8 bq[DB][NTW];
#pragma unroll
    for (int d = 0; d < DA; ++d) {
      int ch = ks * NCW + d;
      ap[d] = *(const half8*)(feat + (size_t)idx[d] * CiPad + ((ch * 32 + lb) & (CiPad - 1)));
    }
#pragma unroll
    for (int d = 0; d < DB; ++d) {
      int ch = ks * NCW + d;
      if (ch >= NCH) ch = NCH - 1;
#pragma unroll
      for (int n = 0; n < NTW; ++n)
        bq[d][n] = *(const half8*)(Bp + ((size_t)ch * NT * 64 + lane) * 8 +
                                   (size_t)(ct0 + n) * 512);
    }
#pragma unroll
    for (int ii = 0; ii < NCW; ++ii) {
      half8 a = ap[ii % DA];
      half8 bt[NTW];
#pragma unroll
      for (int n = 0; n < NTW; ++n) bt[n] = bq[ii % DB][n];
      if (ii + DA < NCW) {
        int nx = ii + DA;
        int ch = ks * NCW + nx;
        ap[ii % DA] = *(const half8*)(feat + (size_t)idx[nx] * CiPad +
                                      ((ch * 32 + lb) & (CiPad - 1)));
      }
      if (ii + DB < NCW) {
        int nx = ii + DB;
        int ch = ks * NCW + nx;
        if (ch >= NCH) ch = NCH - 1;
#pragma unroll
        for (int n = 0; n < NTW; ++n)
          bq[ii % DB][n] = *(const half8*)(Bp + ((size_t)ch * NT * 64 + lane) * 8 +
                                           (size_t)(ct0 + n) * 512);
      }
#pragma unroll
      for (int n = 0; n < NTW; ++n)
        acc[n] = __builtin_amdgcn_mfma_f32_16x16x32_f16(a, bt[n], acc[n], 0, 0, 0);
    }
  }

  const int rl = (lane >> 4) * 4;
  if constexpr (KS > 1) {
    if (ks > 0) {
#pragma unroll
      for (int n = 0; n < NTW; ++n) {
        int lcol = (cg * NTW + n) * 16 + m;
#pragma unroll
        for (int r = 0; r < 4; ++r)
          red[((ks - 1) * RG + rowg) * 16 * CoP + (rl + r) * CoP + lcol] = acc[n][r];
      }
    }
    __syncthreads();
    if (ks > 0) return;
#pragma unroll
    for (int s = 1; s < KS; ++s)
#pragma unroll
      for (int n = 0; n < NTW; ++n) {
        int lcol = (cg * NTW + n) * 16 + m;
#pragma unroll
        for (int r = 0; r < 4; ++r)
          acc[n][r] += red[((s - 1) * RG + rowg) * 16 * CoP + (rl + r) * CoP + lcol];
      }
  }

#pragma unroll
  for (int n = 0; n < NTW; ++n) {
    int col = (ct0 + n) * 16 + m;
    float s_ = sc[col], b_ = bi[col];
#pragma unroll
    for (int r = 0; r < 4; ++r) {
      int orow = i0 + rl + r;
      if (orow < nout)
        out[(size_t)orow * Co + col] = (_Float16)fmaxf(fmaf(acc[n][r], s_, b_), 0.f);
    }
  }
}

// ======== multi-kernel 32x32x16 path (round-0 proven, big layers) ========
template <int K, int CiPad, int Co, int KS, int CG, int CBLK>
__global__ __launch_bounds__(256) void conv_mfma32(
    const _Float16* __restrict__ feat, const _Float16* __restrict__ Bp,
    const int* __restrict__ tbl, const float* __restrict__ sc,
    const float* __restrict__ bi, _Float16* __restrict__ out,
    int nout, int nin) {
  constexpr int NT = Co / 32;
  constexpr int NTE = NT / CBLK;
  constexpr int NTW = NTE / CG;
  constexpr int RG = 4 / (KS * CG);
  static_assert(KS * CG * RG == 4 && RG >= 1 && NT % CBLK == 0 && NTE % CG == 0 && NTW >= 1);
  constexpr int SUB = CiPad / 16;
  constexpr int NKW = (K + KS - 1) / KS;
  constexpr int NC = NKW * SUB;
  constexpr int DA = NC < 8 ? NC : 8;
  constexpr int DB = NC < 2 ? NC : 2;
  constexpr int CoP = NTE * 32 + 4;

  __shared__ float red[(KS > 1) ? (KS - 1) * RG * 32 * CoP : 1];

  if (blockIdx.x == 0 && threadIdx.x < Co)
    out[(size_t)nout * Co + threadIdx.x] = (_Float16)0.f;

  int id = blockIdx.x;
  { int nb = gridDim.x, nb8 = (nb >> 3) << 3;
    if (id < nb8) { int per = nb >> 3; id = (id & 7) * per + (id >> 3); } }
  const int rt = id / CBLK, cb = id % CBLK;
  const int wave = threadIdx.x >> 6, lane = threadIdx.x & 63;
  const int ks = wave % KS;
  const int cg = (wave / KS) % CG;
  const int rowg = wave / (KS * CG);
  const int m = lane & 31, lb = (lane >> 5) * 8, h = lane >> 5;
  const int i0 = (rt * RG + rowg) * 32;
  if constexpr (KS == 1) { if (i0 >= nout) return; }
  const int row = i0 + m;
  const bool rOK = row < nout;
  const int ct0 = cb * NTE + cg * NTW;

  floatx16 acc[NTW];
#pragma unroll
  for (int n = 0; n < NTW; ++n)
#pragma unroll
    for (int r = 0; r < 16; ++r) acc[n][r] = 0.f;

  int idx[NKW];
#pragma unroll
  for (int q = 0; q < NKW; ++q) {
    int k = ks * NKW + q;
    int jj = (rOK && k < K) ? tbl[(size_t)k * nout + row] : -1;
    idx[q] = (jj < 0) ? nin : jj;
  }

  half8 ap[DA]; half8 bq[DB][NTW];
#pragma unroll
  for (int d = 0; d < DA; ++d)
    ap[d] = *(const half8*)(feat + (size_t)idx[d / SUB] * CiPad + (d % SUB) * 16 + lb);
#pragma unroll
  for (int d = 0; d < DB; ++d) {
    int k = ks * NKW + d / SUB;
    int ch = ((k < K) ? k : (K - 1)) * SUB + (d % SUB);
#pragma unroll
    for (int n = 0; n < NTW; ++n)
      bq[d][n] = *(const half8*)(Bp + (size_t)(ch * NT + ct0 + n) * 512 + lane * 8);
  }
#pragma unroll
  for (int ii = 0; ii < NC; ++ii) {
    half8 a = ap[ii % DA];
    half8 bt[NTW];
#pragma unroll
    for (int n = 0; n < NTW; ++n) bt[n] = bq[ii % DB][n];
    if (ii + DA < NC) {
      int nx = ii + DA;
      ap[ii % DA] = *(const half8*)(feat + (size_t)idx[nx / SUB] * CiPad +
                                    (nx % SUB) * 16 + lb);
    }
    if (ii + DB < NC) {
      int nx = ii + DB;
      int k = ks * NKW + nx / SUB;
      int ch = ((k < K) ? k : (K - 1)) * SUB + (nx % SUB);
#pragma unroll
      for (int n = 0; n < NTW; ++n)
        bq[ii % DB][n] = *(const half8*)(Bp + (size_t)(ch * NT + ct0 + n) * 512 + lane * 8);
    }
#pragma unroll
    for (int n = 0; n < NTW; ++n)
      acc[n] = __builtin_amdgcn_mfma_f32_32x32x16_f16(a, bt[n], acc[n], 0, 0, 0);
  }

  if constexpr (KS > 1) {
    if (ks > 0) {
#pragma unroll
      for (int n = 0; n < NTW; ++n) {
        int lcol = (cg * NTW + n) * 32 + m;
#pragma unroll
        for (int reg = 0; reg < 16; ++reg) {
          int r = (reg & 3) + 8 * (reg >> 2) + 4 * h;
          red[((ks - 1) * RG + rowg) * 32 * CoP + r * CoP + lcol] = acc[n][reg];
        }
      }
    }
    __syncthreads();
    if (ks > 0) return;
#pragma unroll
    for (int s = 1; s < KS; ++s)
#pragma unroll
      for (int n = 0; n < NTW; ++n) {
        int lcol = (cg * NTW + n) * 32 + m;
#pragma unroll
        for (int reg = 0; reg < 16; ++reg) {
          int r = (reg & 3) + 8 * (reg >> 2) + 4 * h;
          acc[n][reg] += red[((s - 1) * RG + rowg) * 32 * CoP + r * CoP + lcol];
        }
      }
  }

#pragma unroll
  for (int n = 0; n < NTW; ++n) {
    int col = (ct0 + n) * 32 + m;
    float s_ = sc[col], b_ = bi[col];
#pragma unroll
    for (int reg = 0; reg < 16; ++reg) {
      int orow = i0 + (reg & 3) + 8 * (reg >> 2) + 4 * h;
      if (orow < nout)
        out[(size_t)orow * Co + col] = (_Float16)fmaxf(fmaf(acc[n][reg], s_, b_), 0.f);
    }
  }
}

// ---- persistent-tail pieces ----------------------------------------------

struct LCfg {
  const _Float16* fin; _Float16* fout; const _Float16* bp;
  const int* tbl; const float* sc; const float* bi; int nout, nin;
};
struct TK {
  LCfg L[7];
  const int* batch; int no; float* dout;
  int* bar; int nblk;
};

// one-shot grid barrier; fence ONCE per crossing, spin RELAXED (round-3
// lesson: per-poll ACQUIRE invalidates L2 every iteration = 2.5x cost).
__device__ __forceinline__ void gsync(int* c, int nblk) {
  __syncthreads();
  if (threadIdx.x == 0) {
    __builtin_amdgcn_fence(__ATOMIC_RELEASE, "agent");
    __hip_atomic_fetch_add(c, 1, __ATOMIC_RELAXED, __HIP_MEMORY_SCOPE_AGENT);
    while (__hip_atomic_load(c, __ATOMIC_RELAXED, __HIP_MEMORY_SCOPE_AGENT) < nblk)
      __builtin_amdgcn_s_sleep(8);
    __builtin_amdgcn_fence(__ATOMIC_ACQUIRE, "agent");
  }
  __syncthreads();
}

// per-wave 16x16x32 tail layer (KS=1, no LDS), grid-strided over row tiles
template <int K, int CiPad, int Co, int CB>
__device__ void conv16_layer(const LCfg L, int gw, int GW) {
  constexpr int NT = Co / 16;
  constexpr int NTW = NT / CB;
  static_assert(NT % CB == 0 && NTW >= 1);
  constexpr int DIV = CiPad / 32;
  const int lane = threadIdx.x & 63;
  const int m = lane & 15, lb = (lane >> 4) * 8;
  if (gw == 0) {
    for (int c = lane; c < Co; c += 64)
      L.fout[(size_t)L.nout * Co + c] = (_Float16)0.f;
  }
  const int ntile = ((L.nout + 15) >> 4) * CB;
  for (int it = gw; it < ntile; it += GW) {
    const int rt = it / CB, cb = it % CB;
    const int i0 = rt * 16;
    const int row = i0 + m;
    const bool rOK = row < L.nout;
    const int ct0 = cb * NTW;
    floatx4 acc[NTW];
#pragma unroll
    for (int n = 0; n < NTW; ++n) { floatx4 z = {0, 0, 0, 0}; acc[n] = z; }

    constexpr int NC = K * DIV;
    constexpr int DA = NC < 8 ? NC : 8;
    constexpr int DB = NC < 2 ? NC : 2;
    int idx[K];
#pragma unroll
    for (int q = 0; q < K; ++q) {
      int jj = rOK ? L.tbl[(size_t)q * L.nout + row] : -1;
      idx[q] = (jj < 0) ? L.nin : jj;
    }
    half8 ap[DA]; half8 bq[DB][NTW];
#pragma unroll
    for (int d = 0; d < DA; ++d)
      ap[d] = *(const half8*)(L.fin + (size_t)idx[d / DIV] * CiPad + (d % DIV) * 32 + lb);
#pragma unroll
    for (int d = 0; d < DB; ++d) {
#pragma unroll
      for (int n = 0; n < NTW; ++n)
        bq[d][n] = *(const half8*)(L.bp + ((size_t)d * NT * 64 + lane) * 8 +
                                   (size_t)(ct0 + n) * 512);
    }
#pragma unroll
    for (int ii = 0; ii < NC; ++ii) {
      half8 a = ap[ii % DA];
      half8 bt[NTW];
#pragma unroll
      for (int n = 0; n < NTW; ++n) bt[n] = bq[ii % DB][n];
      if (ii + DA < NC) {
        int nx = ii + DA;
        ap[ii % DA] = *(const half8*)(L.fin + (size_t)idx[nx / DIV] * CiPad +
                                      (nx % DIV) * 32 + lb);
      }
      if (ii + DB < NC) {
        int nx = ii + DB;
#pragma unroll
        for (int n = 0; n < NTW; ++n)
          bq[ii % DB][n] = *(const half8*)(L.bp + ((size_t)nx * NT * 64 + lane) * 8 +
                                           (size_t)(ct0 + n) * 512);
      }
#pragma unroll
      for (int n = 0; n < NTW; ++n)
        acc[n] = __builtin_amdgcn_mfma_f32_16x16x32_f16(a, bt[n], acc[n], 0, 0, 0);
    }

    const int rl = (lane >> 4) * 4;
#pragma unroll
    for (int n = 0; n < NTW; ++n) {
      int col = (ct0 + n) * 16 + m;
      float s_ = L.sc[col], b_ = L.bi[col];
#pragma unroll
      for (int r = 0; r < 4; ++r) {
        int orow = i0 + rl + r;
        if (orow < L.nout)
          L.fout[(size_t)orow * Co + col] = (_Float16)fmaxf(fmaf(acc[n][r], s_, b_), 0.f);
      }
    }
  }
}

// per-wave 32x32x16 tail layer (KS=1, no LDS), grid-strided over row tiles
template <int K, int CiPad, int Co, int CB>
__device__ void conv32_layer(const LCfg L, int gw, int GW) {
  constexpr int NT = Co / 32;
  constexpr int NTW = NT / CB;
  static_assert(NT % CB == 0 && NTW >= 1);
  constexpr int SUB = CiPad / 16;
  constexpr int NC = K * SUB;
  constexpr int DA = NC < 8 ? NC : 8;
  constexpr int DB = NC < 2 ? NC : 2;
  const int lane = threadIdx.x & 63;
  const int m = lane & 31, lb = (lane >> 5) * 8, h = lane >> 5;
  if (gw == 0) {
    for (int c = lane; c < Co; c += 64)
      L.fout[(size_t)L.nout * Co + c] = (_Float16)0.f;
  }
  const int ntile = ((L.nout + 31) >> 5) * CB;
  for (int it = gw; it < ntile; it += GW) {
    const int rt = it / CB, cb = it % CB;
    const int i0 = rt * 32;
    const int row = i0 + m;
    const bool rOK = row < L.nout;
    const int ct0 = cb * NTW;
    floatx16 acc[NTW];
#pragma unroll
    for (int n = 0; n < NTW; ++n)
#pragma unroll
      for (int r = 0; r < 16; ++r) acc[n][r] = 0.f;

    int idx[K];
#pragma unroll
    for (int q = 0; q < K; ++q) {
      int jj = rOK ? L.tbl[(size_t)q * L.nout + row] : -1;
      idx[q] = (jj < 0) ? L.nin : jj;
    }
    half8 ap[DA]; half8 bq[DB][NTW];
#pragma unroll
    for (int d = 0; d < DA; ++d)
      ap[d] = *(const half8*)(L.fin + (size_t)idx[d / SUB] * CiPad + (d % SUB) * 16 + lb);
#pragma unroll
    for (int d = 0; d < DB; ++d) {
#pragma unroll
      for (int n = 0; n < NTW; ++n)
        bq[d][n] = *(const half8*)(L.bp + (size_t)(d * NT + ct0 + n) * 512 + lane * 8);
    }
#pragma unroll
    for (int ii = 0; ii < NC; ++ii) {
      half8 a = ap[ii % DA];
      half8 bt[NTW];
#pragma unroll
      for (int n = 0; n < NTW; ++n) bt[n] = bq[ii % DB][n];
      if (ii + DA < NC) {
        int nx = ii + DA;
        ap[ii % DA] = *(const half8*)(L.fin + (size_t)idx[nx / SUB] * CiPad +
                                      (nx % SUB) * 16 + lb);
      }
      if (ii + DB < NC) {
        int nx = ii + DB;
#pragma unroll
        for (int n = 0; n < NTW; ++n)
          bq[ii % DB][n] = *(const half8*)(L.bp + (size_t)(nx * NT + ct0 + n) * 512 + lane * 8);
      }
#pragma unroll
      for (int n = 0; n < NTW; ++n)
        acc[n] = __builtin_amdgcn_mfma_f32_32x32x16_f16(a, bt[n], acc[n], 0, 0, 0);
    }

#pragma unroll
    for (int n = 0; n < NTW; ++n) {
      int col = (ct0 + n) * 32 + m;
      float s_ = L.sc[col], b_ = L.bi[col];
#pragma unroll
      for (int reg = 0; reg < 16; ++reg) {
        int orow = i0 + (reg & 3) + 8 * (reg >> 2) + 4 * h;
        if (orow < L.nout)
          L.fout[(size_t)orow * Co + col] = (_Float16)fmaxf(fmaf(acc[n][reg], s_, b_), 0.f);
      }
    }
  }
}

// persistent TAIL: stages 3+4+out+segmax (small n => dispatch twins only ran
// ~4 waves/CU anyway; persistence loses no TLP here and saves 7 boundaries).
// 256 blocks x 512 threads (proven geometry, VGPR 128, co-resident on 256 CUs
// at any VGPR<=256, LDS=0 => barrier cannot deadlock).
__global__ __launch_bounds__(512, 2) void tail_persistent(TK P) {
  const int nblk = P.nblk;
  const int gw = blockIdx.x * 8 + (threadIdx.x >> 6);
  const int GW = gridDim.x * 8;
  conv32_layer<27, 32, 64, 2>(P.L[0], gw, GW); gsync(P.bar + 0, nblk); // 3a
  conv32_layer<27, 64, 64, 2>(P.L[1], gw, GW); gsync(P.bar + 1, nblk); // 3b
  conv32_layer<27, 64, 64, 2>(P.L[2], gw, GW); gsync(P.bar + 2, nblk); // 3c
  conv32_layer<27, 64, 64, 2>(P.L[3], gw, GW); gsync(P.bar + 3, nblk); // 4a
  conv32_layer<27, 64, 64, 2>(P.L[4], gw, GW); gsync(P.bar + 4, nblk); // 4b
  conv32_layer<27, 64, 64, 2>(P.L[5], gw, GW); gsync(P.bar + 5, nblk); // 4c
  conv16_layer<3, 64, 128, 4>(P.L[6], gw, GW); gsync(P.bar + 6, nblk); // out
  {
    const _Float16* x = (const _Float16*)P.L[6].fout;
    int c = threadIdx.x & 127;
    int g = blockIdx.x * 4 + (threadIdx.x >> 7);
    int G = gridDim.x * 4;
    int per = (P.no + G - 1) / G;
    int r0 = g * per;
    int rend = min(P.no, r0 + per);
    float mx = 0.f;
    int cb = -1;
    for (int r = r0; r < rend; ++r) {
      int b = P.batch[r];
      if (b != cb) {
        if (cb >= 0) atomicMax((int*)P.dout + ((size_t)cb << 7) + c, __float_as_int(mx));
        cb = b; mx = 0.f;
      }
      mx = fmaxf(mx, (float)x[(size_t)r * 128 + c]);
    }
    if (cb >= 0) atomicMax((int*)P.dout + ((size_t)cb << 7) + c, __float_as_int(mx));
  }
}

extern "C" void kernel_launch(void* const* d_in, const int* in_sizes, int n_in,
                              void* d_out, int out_size, void* d_ws, size_t ws_size,
                              hipStream_t stream) {
  auto I = [&](int idx) { return (const int*)d_in[idx]; };
  auto F = [&](int idx) { return (const float*)d_in[idx]; };

  const int N0  = in_sizes[1];
  const int R1  = in_sizes[3] / 27;
  const int R2s = in_sizes[5] / 27;
  const int n2  = in_sizes[7];
  const int R2  = in_sizes[8] / 27;
  const int R3s = in_sizes[10] / 27;
  const int n3  = in_sizes[12];
  const int R3  = in_sizes[13] / 27;
  const int R4s = in_sizes[15] / 27;
  const int n4  = in_sizes[17];
  const int R4  = in_sizes[18] / 27;
  const int Ro  = in_sizes[20] / 3;
  const int no  = in_sizes[22];

  const int wIdx[12] = {23, 26, 29, 32, 35, 38, 41, 44, 47, 50, 53, 56};
  const int Ks[12]   = {27, 27, 27, 27, 27, 27, 27, 27, 27, 27, 27, 3};
  const int Cis[12]  = {4, 16, 16, 32, 32, 32, 64, 64, 64, 64, 64, 64};
  const int Cos[12]  = {16, 16, 32, 32, 32, 64, 64, 64, 64, 64, 64, 128};
  const int P32[12]  = {0, 0, 0, 1, 1, 1, 1, 1, 1, 1, 1, 0};
  WPs P;
  int wtot = 0;
  int bpOff[12];
  for (int l = 0; l < 12; ++l) {
    int cip = Cis[l] < 8 ? 8 : Cis[l];
    int sz;
    if (P32[l]) sz = Ks[l] * (cip / 16) * (Cos[l] / 32) * 512;
    else        sz = ((Ks[l] * cip + 31) / 32) * (Cos[l] / 16) * 512;
    P.d[l].W = F(wIdx[l]);
    P.d[l].K = Ks[l]; P.d[l].Ci = Cis[l]; P.d[l].CiPad = cip; P.d[l].Co = Cos[l];
    P.d[l].start = wtot; P.d[l].end = wtot + sz; P.d[l].off = wtot; P.d[l].p32 = P32[l];
    bpOff[l] = wtot;
    wtot += sz;
  }

  RBs RP;
  const int rbRin[8]  = {3, 5, 8, 10, 13, 15, 18, 20};
  const int rbRs[8]   = {R1, R2s, R2, R3s, R3, R4s, R4, Ro};
  const int rbKs[8]   = {27, 27, 27, 27, 27, 27, 27, 3};
  const int rbNout[8] = {N0, n2, n2, n3, n3, n4, n4, no};
  size_t tblOff[8];
  size_t totTbl = 0;
  int totFill = 0;
  for (int l = 0; l < 8; ++l) {
    tblOff[l] = totTbl;
    totTbl += (size_t)rbNout[l] * rbKs[l];
    RP.d[l].rin = I(rbRin[l]);
    RP.d[l].rout = I(rbRin[l] + 1);
    RP.d[l].K = rbKs[l]; RP.d[l].R = rbRs[l]; RP.d[l].nout = rbNout[l];
    RP.d[l].start = totFill;
    totFill += rbKs[l] * rbRs[l];
    RP.d[l].end = totFill;
    RP.d[l].off = (int)tblOff[l];
  }

  size_t S = (size_t)(N0 + 1) * 16;
  auto smax = [&](size_t v) { if (v > S) S = v; };
  smax((size_t)(n2 + 1) * 32);
  smax((size_t)(n3 + 1) * 64);
  smax((size_t)(n4 + 1) * 64);
  smax((size_t)(no + 1) * 128);
  S = (S + 7) & ~(size_t)7;

  _Float16* h = (_Float16*)d_ws;
  size_t off = 0;
  _Float16* f0 = h + off;   off += (size_t)(N0 + 1) * 8;
  _Float16* bufA = h + off; off += S;
  _Float16* bufB = h + off; off += S;
  _Float16* Bp = h + off;   off += (size_t)((wtot + 7) & ~7);
  int* tblBase = (int*)(h + off);
  int* bar = tblBase + totTbl;

  // dispatch 1: fused prep (feat + zero d_out + tbl=-1 + bar=0 + weights)
  P.vox = F(0); P.vnp = I(1); P.f0 = f0;
  P.featTot = (N0 + 1) * 8; P.N0 = N0;
  P.dout = (float*)d_out; P.outTot = out_size;
  P.tbl = tblBase; P.tblTot = (int)totTbl;
  P.bar = bar;
  int prepTot = P.featTot + P.outTot + P.tblTot + 16 + wtot;
  prep_all<<<cdiv_i(prepTot, 256), 256, 0, stream>>>(P, Bp, prepTot);

  // dispatch 2: all rulebook inversions
  rb_fill_all<<<cdiv_i(totFill, 256), 256, 0, stream>>>(RP, tblBase, totFill);

  const int l2rb[12] = {0, 0, 1, 2, 2, 3, 4, 4, 5, 6, 6, 7};
  const int* tblL[12];
  for (int l = 0; l < 12; ++l) tblL[l] = tblBase + tblOff[l2rb[l]];

#define CONV16(Kk, CIP, CO, KSv, CGv, CBv, IN, LI, OUTB, NOUT, NIN)           \
  do {                                                                        \
    constexpr int rowsPerBlk = (4 / (KSv * CGv)) * 16;                        \
    int nblk = cdiv_i(NOUT, rowsPerBlk) * CBv;                                \
    conv_mfma<Kk, CIP, CO, KSv, CGv, CBv><<<nblk, 256, 0, stream>>>(          \
        IN, Bp + bpOff[LI], tblL[LI], F(wIdx[LI] + 1), F(wIdx[LI] + 2),       \
        OUTB, NOUT, NIN);                                                     \
  } while (0)
#define CONV32(Kk, CIP, CO, KSv, CGv, CBv, IN, LI, OUTB, NOUT, NIN)           \
  do {                                                                        \
    constexpr int rowsPerBlk = (4 / (KSv * CGv)) * 32;                        \
    int nblk = cdiv_i(NOUT, rowsPerBlk) * CBv;                                \
    conv_mfma32<Kk, CIP, CO, KSv, CGv, CBv><<<nblk, 256, 0, stream>>>(        \
        IN, Bp + bpOff[LI], tblL[LI], F(wIdx[LI] + 1), F(wIdx[LI] + 2),       \
        OUTB, NOUT, NIN);                                                     \
  } while (0)

  // dispatches 3-7: big layers, round-0 proven configs
  CONV16(27, 8, 16, 1, 1, 1, f0, 0, bufA, N0, N0);     // conv_in
  CONV16(27, 16, 16, 2, 1, 1, bufA, 1, bufB, N0, N0);  // conv1
  CONV16(27, 16, 32, 2, 1, 1, bufB, 2, bufA, n2, N0);  // conv2a
  CONV32(27, 32, 32, 4, 1, 1, bufA, 3, bufB, n2, n2);  // conv2b
  CONV32(27, 32, 32, 4, 1, 1, bufB, 4, bufA, n2, n2);  // conv2c
#undef CONV16
#undef CONV32

  // dispatch 8: persistent tail (conv3a..conv_out + segmax)
  TK T;
  const int tl[7]     = {5, 6, 7, 8, 9, 10, 11};
  const int touts[7]  = {n3, n3, n3, n4, n4, n4, no};
  const int tins[7]   = {n2, n3, n3, n3, n4, n4, n4};
  // wiring: bufA(in) ->B ->A ->B ->A ->B ->A ->B(conv_out out)
  _Float16* tb[8];
  tb[0] = bufA;
  for (int i = 0; i < 7; ++i) tb[i + 1] = (i & 1) ? bufA : bufB;
  for (int i = 0; i < 7; ++i) {
    int l = tl[i];
    T.L[i].fin  = tb[i];
    T.L[i].fout = tb[i + 1];
    T.L[i].bp   = Bp + bpOff[l];
    T.L[i].tbl  = tblL[l];
    T.L[i].sc   = F(wIdx[l] + 1);
    T.L[i].bi   = F(wIdx[l] + 2);
    T.L[i].nout = touts[i];
    T.L[i].nin  = tins[i];
  }
  T.batch = I(22); T.no = no; T.dout = (float*)d_out;
  T.bar = bar; T.nblk = 256;
  tail_persistent<<<256, 512, 0, stream>>>(T);
}

// Round 8
// 433.093 us; speedup vs baseline: 4.9235x; 1.4336x over previous
//
#include <hip/hip_runtime.h>
#include <cstddef>
#include <cstdint>

typedef _Float16 half8 __attribute__((ext_vector_type(8)));
typedef float floatx4 __attribute__((ext_vector_type(4)));
typedef float floatx16 __attribute__((ext_vector_type(16)));

static inline int cdiv_i(int a, int b) { return (a + b - 1) / b; }

// ---- fused rulebook inversion, TRANSPOSED tables: tbl[k*nout + o] = in
struct RB { const int* rin; const int* rout; int K, R, nout, start, end, off; };
struct RBs { RB d[8]; };
__global__ void rb_fill_all(RBs P, int* __restrict__ tbl, int total) {
  int idx = blockIdx.x * blockDim.x + threadIdx.x;
  if (idx >= total) return;
#pragma unroll
  for (int l = 0; l < 8; ++l) {
    if (idx >= P.d[l].start && idx < P.d[l].end) {
      const RB rb = P.d[l];
      int e = idx - rb.start;
      int o = rb.rout[e];
      if ((unsigned)o < (unsigned)rb.nout) {
        int k = e / rb.R;
        tbl[rb.off + (size_t)k * rb.nout + o] = rb.rin[e];
      }
    }
  }
}

__global__ void tbl_fill_kernel(const int* __restrict__ rin,
                                const int* __restrict__ rout,
                                int* __restrict__ tbl, int K, int R, int nout) {
  int e = blockIdx.x * blockDim.x + threadIdx.x;
  if (e >= K * R) return;
  int o = rout[e];
  if ((unsigned)o >= (unsigned)nout) return;
  int k = e / R;
  tbl[(size_t)k * nout + o] = rin[e];
}

// ---- fused prep: feat (f16 pad8) + zero d_out + weight pack
struct WP { const float* W; int K, Ci, CiPad, Co, start, end, off, p32; };
struct WPs {
  WP d[12];
  const float* vox; const int* vnp; _Float16* f0; int featTot, N0;
  float* dout; int outTot, wStart, wEnd;
};
__global__ void prep_all(WPs P, _Float16* __restrict__ Bp, int total) {
  int idx = blockIdx.x * blockDim.x + threadIdx.x;
  if (idx >= total) return;
  if (idx < P.featTot) {
    int i = idx >> 3, c = idx & 7;
    float v = 0.f;
    if (i < P.N0 && c < 4) {
      const float* p = P.vox + (size_t)i * 20 + c;
      v = (p[0] + p[4] + p[8] + p[12] + p[16]) / fmaxf((float)P.vnp[i], 1.f);
    }
    P.f0[idx] = (_Float16)v;
    return;
  }
  if (idx < P.featTot + P.outTot) {
    P.dout[idx - P.featTot] = 0.f;
    return;
  }
  int widx = idx - P.featTot - P.outTot;
#pragma unroll
  for (int l = 0; l < 12; ++l) {
    if (widx >= P.d[l].start && widx < P.d[l].end) {
      const WP w = P.d[l];
      int e = widx - w.start;
      int j = e & 7;
      int lane = (e >> 3) & 63;
      int rest = e >> 9;
      float v;
      if (w.p32) {
        int NT = w.Co >> 5;
        int t = rest % NT, ch = rest / NT;
        int SUB = w.CiPad >> 4;
        int ko = ch / SUB, s = ch % SUB;
        int ci = s * 16 + ((lane >> 5) << 3) + j;
        int col = t * 32 + (lane & 31);
        v = w.W[((size_t)ko * w.Ci + ci) * w.Co + col];
      } else {
        int NT = w.Co >> 4;
        int t = rest % NT, ch = rest / NT;
        int kk = ch * 32 + ((lane >> 4) << 3) + j;
        int k = kk / w.CiPad, ci = kk % w.CiPad;
        int n = t * 16 + (lane & 15);
        v = (k < w.K && ci < w.Ci) ? w.W[((size_t)k * w.Ci + ci) * w.Co + n] : 0.f;
      }
      Bp[w.off + e] = (_Float16)v;
    }
  }
}

// ======== 16x16x32 path ========
template <int K, int CiPad, int Co, int KS, int CG, int CBLK>
__global__ __launch_bounds__(256) void conv_mfma(
    const _Float16* __restrict__ feat, const _Float16* __restrict__ Bp,
    const int* __restrict__ tbl, const float* __restrict__ sc,
    const float* __restrict__ bi, _Float16* __restrict__ out,
    int nout, int nin) {
  constexpr int NT = Co / 16;
  constexpr int NTE = NT / CBLK;
  constexpr int NTW = NTE / CG;
  constexpr int RG = 4 / (KS * CG);
  static_assert(KS * CG * RG == 4 && RG >= 1 && NT % CBLK == 0 && NTE % CG == 0);
  constexpr int NCH = (K * CiPad + 31) / 32;
  constexpr int L2C = (CiPad == 8) ? 3 : 4;
  constexpr int DIV = (CiPad >= 32) ? (CiPad / 32) : 1;
  constexpr int CoP = NTE * 16 + 4;

  __shared__ float red[(KS > 1) ? (KS - 1) * RG * 16 * CoP : 1];

  if (blockIdx.x == 0 && threadIdx.x < Co)
    out[(size_t)nout * Co + threadIdx.x] = (_Float16)0.f;

  int id = blockIdx.x;
  { int nb = gridDim.x, nb8 = (nb >> 3) << 3;
    if (id < nb8) { int per = nb >> 3; id = (id & 7) * per + (id >> 3); } }
  const int rt = id / CBLK, cb = id % CBLK;
  const int wave = threadIdx.x >> 6, lane = threadIdx.x & 63;
  const int ks = wave % KS;
  const int cg = (wave / KS) % CG;
  const int rowg = wave / (KS * CG);
  const int m = lane & 15, lb = (lane >> 4) * 8;
  const int i0 = (rt * RG + rowg) * 16;
  if constexpr (KS == 1) { if (i0 >= nout) return; }
  const int row = i0 + m;
  const bool rOK = row < nout;
  const int ct0 = cb * NTE + cg * NTW;

  floatx4 acc[NTW];
#pragma unroll
  for (int n = 0; n < NTW; ++n) { floatx4 z = {0,0,0,0}; acc[n] = z; }

  if constexpr (CiPad >= 32) {
    constexpr int NKW = (K + KS - 1) / KS;
    constexpr int NC = NKW * DIV;
    constexpr int DA = NC < 8 ? NC : 8;
    constexpr int DB = NC < 2 ? NC : 2;
    int idx[NKW];
#pragma unroll
    for (int q = 0; q < NKW; ++q) {
      int k = ks * NKW + q;
      int jj = (rOK && k < K) ? tbl[(size_t)k * nout + row] : -1;
      idx[q] = (jj < 0) ? nin : jj;
    }
    half8 ap[DA]; half8 bq[DB][NTW];
#pragma unroll
    for (int d = 0; d < DA; ++d)
      ap[d] = *(const half8*)(feat + (size_t)idx[d / DIV] * CiPad + (d % DIV) * 32 + lb);
#pragma unroll
    for (int d = 0; d < DB; ++d) {
      int k = ks * NKW + d / DIV;
      int ch = ((k < K) ? k : (K - 1)) * DIV + (d % DIV);
#pragma unroll
      for (int n = 0; n < NTW; ++n)
        bq[d][n] = *(const half8*)(Bp + ((size_t)ch * NT * 64 + lane) * 8 +
                                   (size_t)(ct0 + n) * 512);
    }
#pragma unroll
    for (int ii = 0; ii < NC; ++ii) {
      half8 a = ap[ii % DA];
      half8 bt[NTW];
#pragma unroll
      for (int n = 0; n < NTW; ++n) bt[n] = bq[ii % DB][n];
      if (ii + DA < NC) {
        int nx = ii + DA;
        ap[ii % DA] = *(const half8*)(feat + (size_t)idx[nx / DIV] * CiPad +
                                      (nx % DIV) * 32 + lb);
      }
      if (ii + DB < NC) {
        int nx = ii + DB;
        int k = ks * NKW + nx / DIV;
        int ch = ((k < K) ? k : (K - 1)) * DIV + (nx % DIV);
#pragma unroll
        for (int n = 0; n < NTW; ++n)
          bq[ii % DB][n] = *(const half8*)(Bp + ((size_t)ch * NT * 64 + lane) * 8 +
                                           (size_t)(ct0 + n) * 512);
      }
#pragma unroll
      for (int n = 0; n < NTW; ++n)
        acc[n] = __builtin_amdgcn_mfma_f32_16x16x32_f16(a, bt[n], acc[n], 0, 0, 0);
    }
  } else {
    constexpr int NCW = (NCH + KS - 1) / KS;
    constexpr int DA = NCW < 8 ? NCW : 8;
    constexpr int DB = NCW < 2 ? NCW : 2;
    int idx[NCW];
#pragma unroll
    for (int q = 0; q < NCW; ++q) {
      int ch = ks * NCW + q;
      int ko = (ch * 32 + lb) >> L2C;
      int jj = (rOK && ko < K && ch < NCH) ? tbl[(size_t)ko * nout + row] : -1;
      idx[q] = (jj < 0) ? nin : jj;
    }
    half8 ap[DA]; half8 bq[DB][NTW];
#pragma unroll
    for (int d = 0; d < DA; ++d) {
      int ch = ks * NCW + d;
      ap[d] = *(const half8*)(feat + (size_t)idx[d] * CiPad + ((ch * 32 + lb) & (CiPad - 1)));
    }
#pragma unroll
    for (int d = 0; d < DB; ++d) {
      int ch = ks * NCW + d;
      if (ch >= NCH) ch = NCH - 1;
#pragma unroll
      for (int n = 0; n < NTW; ++n)
        bq[d][n] = *(const half8*)(Bp + ((size_t)ch * NT * 64 + lane) * 8 +
                                   (size_t)(ct0 + n) * 512);
    }
#pragma unroll
    for (int ii = 0; ii < NCW; ++ii) {
      half8 a = ap[ii % DA];
      half8 bt[NTW];
#pragma unroll
      for (int n = 0; n < NTW; ++n) bt[n] = bq[ii % DB][n];
      if (ii + DA < NCW) {
        int nx = ii + DA;
        int ch = ks * NCW + nx;
        ap[ii % DA] = *(const half8*)(feat + (size_t)idx[nx] * CiPad +
                                      ((ch * 32 + lb) & (CiPad - 1)));
      }
      if (ii + DB < NCW) {
        int nx = ii + DB;
        int ch = ks * NCW + nx;
        if (ch >= NCH) ch = NCH - 1;
#pragma unroll
        for (int n = 0; n < NTW; ++n)
          bq[ii % DB][n] = *(const half8*)(Bp + ((size_t)ch * NT * 64 + lane) * 8 +
                                           (size_t)(ct0 + n) * 512);
      }
#pragma unroll
      for (int n = 0; n < NTW; ++n)
        acc[n] = __builtin_amdgcn_mfma_f32_16x16x32_f16(a, bt[n], acc[n], 0, 0, 0);
    }
  }

  const int rl = (lane >> 4) * 4;
  if constexpr (KS > 1) {
    if (ks > 0) {
#pragma unroll
      for (int n = 0; n < NTW; ++n) {
        int lcol = (cg * NTW + n) * 16 + m;
#pragma unroll
        for (int r = 0; r < 4; ++r)
          red[((ks - 1) * RG + rowg) * 16 * CoP + (rl + r) * CoP + lcol] = acc[n][r];
      }
    }
    __syncthreads();
    if (ks > 0) return;
#pragma unroll
    for (int s = 1; s < KS; ++s)
#pragma unroll
      for (int n = 0; n < NTW; ++n) {
        int lcol = (cg * NTW + n) * 16 + m;
#pragma unroll
        for (int r = 0; r < 4; ++r)
          acc[n][r] += red[((s - 1) * RG + rowg) * 16 * CoP + (rl + r) * CoP + lcol];
      }
  }

#pragma unroll
  for (int n = 0; n < NTW; ++n) {
    int col = (ct0 + n) * 16 + m;
    float s_ = sc[col], b_ = bi[col];
#pragma unroll
    for (int r = 0; r < 4; ++r) {
      int orow = i0 + rl + r;
      if (orow < nout)
        out[(size_t)orow * Co + col] = (_Float16)fmaxf(fmaf(acc[n][r], s_, b_), 0.f);
    }
  }
}

// ======== 32x32x16 path (Ci>=32 heavy layers), contiguous-k per wave ========
template <int K, int CiPad, int Co, int KS, int CG, int CBLK>
__global__ __launch_bounds__(256) void conv_mfma32(
    const _Float16* __restrict__ feat, const _Float16* __restrict__ Bp,
    const int* __restrict__ tbl, const float* __restrict__ sc,
    const float* __restrict__ bi, _Float16* __restrict__ out,
    int nout, int nin) {
  constexpr int NT = Co / 32;
  constexpr int NTE = NT / CBLK;
  constexpr int NTW = NTE / CG;
  constexpr int RG = 4 / (KS * CG);
  static_assert(KS * CG * RG == 4 && RG >= 1 && NT % CBLK == 0 && NTE % CG == 0 && NTW >= 1);
  constexpr int SUB = CiPad / 16;
  constexpr int NKW = (K + KS - 1) / KS;
  constexpr int NC = NKW * SUB;
  constexpr int DA = NC < 8 ? NC : 8;
  constexpr int DB = NC < 2 ? NC : 2;
  constexpr int CoP = NTE * 32 + 4;

  __shared__ float red[(KS > 1) ? (KS - 1) * RG * 32 * CoP : 1];

  if (blockIdx.x == 0 && threadIdx.x < Co)
    out[(size_t)nout * Co + threadIdx.x] = (_Float16)0.f;

  int id = blockIdx.x;
  { int nb = gridDim.x, nb8 = (nb >> 3) << 3;
    if (id < nb8) { int per = nb >> 3; id = (id & 7) * per + (id >> 3); } }
  const int rt = id / CBLK, cb = id % CBLK;
  const int wave = threadIdx.x >> 6, lane = threadIdx.x & 63;
  const int ks = wave % KS;
  const int cg = (wave / KS) % CG;
  const int rowg = wave / (KS * CG);
  const int m = lane & 31, lb = (lane >> 5) * 8, h = lane >> 5;
  const int i0 = (rt * RG + rowg) * 32;
  if constexpr (KS == 1) { if (i0 >= nout) return; }
  const int row = i0 + m;
  const bool rOK = row < nout;
  const int ct0 = cb * NTE + cg * NTW;

  floatx16 acc[NTW];
#pragma unroll
  for (int n = 0; n < NTW; ++n)
#pragma unroll
    for (int r = 0; r < 16; ++r) acc[n][r] = 0.f;

  int idx[NKW];
#pragma unroll
  for (int q = 0; q < NKW; ++q) {
    int k = ks * NKW + q;
    int jj = (rOK && k < K) ? tbl[(size_t)k * nout + row] : -1;
    idx[q] = (jj < 0) ? nin : jj;
  }

  half8 ap[DA]; half8 bq[DB][NTW];
#pragma unroll
  for (int d = 0; d < DA; ++d)
    ap[d] = *(const half8*)(feat + (size_t)idx[d / SUB] * CiPad + (d % SUB) * 16 + lb);
#pragma unroll
  for (int d = 0; d < DB; ++d) {
    int k = ks * NKW + d / SUB;
    int ch = ((k < K) ? k : (K - 1)) * SUB + (d % SUB);
#pragma unroll
    for (int n = 0; n < NTW; ++n)
      bq[d][n] = *(const half8*)(Bp + (size_t)(ch * NT + ct0 + n) * 512 + lane * 8);
  }
#pragma unroll
  for (int ii = 0; ii < NC; ++ii) {
    half8 a = ap[ii % DA];
    half8 bt[NTW];
#pragma unroll
    for (int n = 0; n < NTW; ++n) bt[n] = bq[ii % DB][n];
    if (ii + DA < NC) {
      int nx = ii + DA;
      ap[ii % DA] = *(const half8*)(feat + (size_t)idx[nx / SUB] * CiPad +
                                    (nx % SUB) * 16 + lb);
    }
    if (ii + DB < NC) {
      int nx = ii + DB;
      int k = ks * NKW + nx / SUB;
      int ch = ((k < K) ? k : (K - 1)) * SUB + (nx % SUB);
#pragma unroll
      for (int n = 0; n < NTW; ++n)
        bq[ii % DB][n] = *(const half8*)(Bp + (size_t)(ch * NT + ct0 + n) * 512 + lane * 8);
    }
#pragma unroll
    for (int n = 0; n < NTW; ++n)
      acc[n] = __builtin_amdgcn_mfma_f32_32x32x16_f16(a, bt[n], acc[n], 0, 0, 0);
  }

  if constexpr (KS > 1) {
    if (ks > 0) {
#pragma unroll
      for (int n = 0; n < NTW; ++n) {
        int lcol = (cg * NTW + n) * 32 + m;
#pragma unroll
        for (int reg = 0; reg < 16; ++reg) {
          int r = (reg & 3) + 8 * (reg >> 2) + 4 * h;
          red[((ks - 1) * RG + rowg) * 32 * CoP + r * CoP + lcol] = acc[n][reg];
        }
      }
    }
    __syncthreads();
    if (ks > 0) return;
#pragma unroll
    for (int s = 1; s < KS; ++s)
#pragma unroll
      for (int n = 0; n < NTW; ++n) {
        int lcol = (cg * NTW + n) * 32 + m;
#pragma unroll
        for (int reg = 0; reg < 16; ++reg) {
          int r = (reg & 3) + 8 * (reg >> 2) + 4 * h;
          acc[n][reg] += red[((s - 1) * RG + rowg) * 32 * CoP + r * CoP + lcol];
        }
      }
  }

#pragma unroll
  for (int n = 0; n < NTW; ++n) {
    int col = (ct0 + n) * 32 + m;
    float s_ = sc[col], b_ = bi[col];
#pragma unroll
    for (int reg = 0; reg < 16; ++reg) {
      int orow = i0 + (reg & 3) + 8 * (reg >> 2) + 4 * h;
      if (orow < nout)
        out[(size_t)orow * Co + col] = (_Float16)fmaxf(fmaf(acc[n][reg], s_, b_), 0.f);
    }
  }
}

// ---- two-stage segment max; batch_out nondecreasing; one atomic per run.
__global__ __launch_bounds__(256) void segmax2(const _Float16* __restrict__ x,
                                               const int* __restrict__ batch,
                                               int n, float* __restrict__ out) {
  const int RPB = 128;
  int c = threadIdx.x & 127, g = threadIdx.x >> 7;
  int r0 = blockIdx.x * RPB + g;
  int rend = min(n, blockIdx.x * RPB + RPB);
  float mx = 0.f;
  int cb = -1;
  for (int r = r0; r < rend; r += 2) {
    int b = batch[r];
    if (b != cb) {
      if (cb >= 0) atomicMax((int*)out + ((size_t)cb << 7) + c, __float_as_int(mx));
      cb = b; mx = 0.f;
    }
    mx = fmaxf(mx, (float)x[(size_t)r * 128 + c]);
  }
  if (cb >= 0) atomicMax((int*)out + ((size_t)cb << 7) + c, __float_as_int(mx));
}

extern "C" void kernel_launch(void* const* d_in, const int* in_sizes, int n_in,
                              void* d_out, int out_size, void* d_ws, size_t ws_size,
                              hipStream_t stream) {
  auto I = [&](int idx) { return (const int*)d_in[idx]; };
  auto F = [&](int idx) { return (const float*)d_in[idx]; };

  const int N0  = in_sizes[1];
  const int R1  = in_sizes[3] / 27;
  const int R2s = in_sizes[5] / 27;
  const int n2  = in_sizes[7];
  const int R2  = in_sizes[8] / 27;
  const int R3s = in_sizes[10] / 27;
  const int n3  = in_sizes[12];
  const int R3  = in_sizes[13] / 27;
  const int R4s = in_sizes[15] / 27;
  const int n4  = in_sizes[17];
  const int R4  = in_sizes[18] / 27;
  const int Ro  = in_sizes[20] / 3;
  const int no  = in_sizes[22];

  const int wIdx[12] = {23, 26, 29, 32, 35, 38, 41, 44, 47, 50, 53, 56};
  const int Ks[12]   = {27, 27, 27, 27, 27, 27, 27, 27, 27, 27, 27, 3};
  const int Cis[12]  = {4, 16, 16, 32, 32, 32, 64, 64, 64, 64, 64, 64};
  const int Cos[12]  = {16, 16, 32, 32, 32, 64, 64, 64, 64, 64, 64, 128};
  const int P32[12]  = {0, 0, 0, 1, 1, 1, 1, 1, 1, 1, 1, 0};
  WPs P;
  int wtot = 0;
  int bpOff[12];
  for (int l = 0; l < 12; ++l) {
    int cip = Cis[l] < 8 ? 8 : Cis[l];
    int sz;
    if (P32[l]) sz = Ks[l] * (cip / 16) * (Cos[l] / 32) * 512;
    else        sz = ((Ks[l] * cip + 31) / 32) * (Cos[l] / 16) * 512;
    P.d[l].W = F(wIdx[l]);
    P.d[l].K = Ks[l]; P.d[l].Ci = Cis[l]; P.d[l].CiPad = cip; P.d[l].Co = Cos[l];
    P.d[l].start = wtot; P.d[l].end = wtot + sz; P.d[l].off = wtot; P.d[l].p32 = P32[l];
    bpOff[l] = wtot;
    wtot += sz;
  }

  RBs RP;
  const int rbRin[8]  = {3, 5, 8, 10, 13, 15, 18, 20};
  const int rbRs[8]   = {R1, R2s, R2, R3s, R3, R4s, R4, Ro};
  const int rbKs[8]   = {27, 27, 27, 27, 27, 27, 27, 3};
  const int rbNout[8] = {N0, n2, n2, n3, n3, n4, n4, no};
  size_t tblInts[8], tblOff[8];
  size_t totTbl = 0;
  int totFill = 0;
  for (int l = 0; l < 8; ++l) {
    tblInts[l] = (size_t)rbNout[l] * rbKs[l];
    tblOff[l] = totTbl;
    totTbl += tblInts[l];
    RP.d[l].rin = I(rbRin[l]);
    RP.d[l].rout = I(rbRin[l] + 1);
    RP.d[l].K = rbKs[l]; RP.d[l].R = rbRs[l]; RP.d[l].nout = rbNout[l];
    RP.d[l].start = totFill;
    totFill += rbKs[l] * rbRs[l];
    RP.d[l].end = totFill;
    RP.d[l].off = (int)tblOff[l];
  }

  size_t S = (size_t)(N0 + 1) * 16;
  auto smax = [&](size_t v) { if (v > S) S = v; };
  smax((size_t)(n2 + 1) * 32);
  smax((size_t)(n3 + 1) * 64);
  smax((size_t)(n4 + 1) * 64);
  smax((size_t)(no + 1) * 128);
  S = (S + 7) & ~(size_t)7;

  _Float16* h = (_Float16*)d_ws;
  size_t off = 0;
  _Float16* f0 = h + off;   off += (size_t)(N0 + 1) * 8;
  _Float16* bufA = h + off; off += S;
  _Float16* bufB = h + off; off += S;
  _Float16* Bp = h + off;   off += (size_t)((wtot + 7) & ~7);
  int* tblBase = (int*)(h + off);
  size_t usedBytes = off * 2;
  bool prebuilt = (usedBytes + totTbl * 4 <= ws_size);

  // fused prep: feat + zero d_out + weight pack
  P.vox = F(0); P.vnp = I(1); P.f0 = f0;
  P.featTot = (N0 + 1) * 8; P.N0 = N0;
  P.dout = (float*)d_out; P.outTot = out_size;
  int prepTot = P.featTot + P.outTot + wtot;
  prep_all<<<cdiv_i(prepTot, 256), 256, 0, stream>>>(P, Bp, prepTot);

  const int l2rb[12] = {0, 0, 1, 2, 2, 3, 4, 4, 5, 6, 6, 7};
  const int* tblL[12];
  if (prebuilt) {
    hipMemsetAsync(tblBase, 0xFF, totTbl * 4, stream);
    rb_fill_all<<<cdiv_i(totFill, 256), 256, 0, stream>>>(RP, tblBase, totFill);
    for (int l = 0; l < 12; ++l) tblL[l] = tblBase + tblOff[l2rb[l]];
  } else {
    for (int l = 0; l < 12; ++l) tblL[l] = tblBase;
  }
  auto buildSeq = [&](int rb) {
    if (prebuilt) return;
    hipMemsetAsync(tblBase, 0xFF, tblInts[rb] * 4, stream);
    tbl_fill_kernel<<<cdiv_i(rbKs[rb] * rbRs[rb], 256), 256, 0, stream>>>(
        I(rbRin[rb]), I(rbRin[rb] + 1), tblBase, rbKs[rb], rbRs[rb], rbNout[rb]);
  };

#define CONV16(Kk, CIP, CO, KSv, CGv, CBv, IN, LI, OUTB, NOUT, NIN)           \
  do {                                                                        \
    constexpr int rowsPerBlk = (4 / (KSv * CGv)) * 16;                        \
    int nblk = cdiv_i(NOUT, rowsPerBlk) * CBv;                                \
    conv_mfma<Kk, CIP, CO, KSv, CGv, CBv><<<nblk, 256, 0, stream>>>(          \
        IN, Bp + bpOff[LI], tblL[LI], F(wIdx[LI] + 1), F(wIdx[LI] + 2),       \
        OUTB, NOUT, NIN);                                                     \
  } while (0)
#define CONV32(Kk, CIP, CO, KSv, CGv, CBv, IN, LI, OUTB, NOUT, NIN)           \
  do {                                                                        \
    constexpr int rowsPerBlk = (4 / (KSv * CGv)) * 32;                        \
    int nblk = cdiv_i(NOUT, rowsPerBlk) * CBv;                                \
    conv_mfma32<Kk, CIP, CO, KSv, CGv, CBv><<<nblk, 256, 0, stream>>>(        \
        IN, Bp + bpOff[LI], tblL[LI], F(wIdx[LI] + 1), F(wIdx[LI] + 2),       \
        OUTB, NOUT, NIN);                                                     \
  } while (0)

  // stage 1 (narrow -> 16x16 path)
  buildSeq(0);
  CONV16(27, 8, 16, 1, 1, 1, f0, 0, bufA, N0, N0);     // conv_in
  CONV16(27, 16, 16, 2, 1, 1, bufA, 1, bufB, N0, N0);  // conv1
  // stage 2
  buildSeq(1);
  CONV16(27, 16, 32, 2, 1, 1, bufB, 2, bufA, n2, N0);  // conv2a
  buildSeq(2);
  CONV32(27, 32, 32, 4, 1, 1, bufA, 3, bufB, n2, n2);  // conv2b
  CONV32(27, 32, 32, 4, 1, 1, bufB, 4, bufA, n2, n2);  // conv2c
  // stage 3
  buildSeq(3);
  CONV32(27, 32, 64, 4, 1, 1, bufA, 5, bufB, n3, n2);  // conv3a
  buildSeq(4);
  CONV32(27, 64, 64, 4, 1, 1, bufB, 6, bufA, n3, n3);  // conv3b
  CONV32(27, 64, 64, 4, 1, 1, bufA, 7, bufB, n3, n3);  // conv3c
  // stage 4
  buildSeq(5);
  CONV32(27, 64, 64, 4, 1, 1, bufB, 8, bufA, n4, n3);  // conv4a
  buildSeq(6);
  CONV32(27, 64, 64, 4, 1, 1, bufA, 9, bufB, n4, n4);  // conv4b
  CONV32(27, 64, 64, 4, 1, 1, bufB, 10, bufA, n4, n4); // conv4c
  // out conv (K=3, Co=128) -> 16x16 path
  buildSeq(7);
  CONV16(3, 64, 128, 2, 2, 2, bufA, 11, bufB, no, n4); // conv_out
  segmax2<<<cdiv_i(no, 128), 256, 0, stream>>>(bufB, I(22), no, (float*)d_out);
#undef CONV16
#undef CONV32
}